// Round 3
// baseline (2302.488 us; speedup 1.0000x reference)
//
#include <hip/hip_runtime.h>
#include <hip/hip_bf16.h>
#include <math.h>

using bf16 = __hip_bfloat16;

#define DEV __device__ __forceinline__

// B=16, CIN=256, N=H*W=1024, INNER=512, CTX_N=77, CTX_D=768, HEADS=8, DH=64.
// External tensors' dtype (fp32 vs bf16) is detected at runtime by probe_dtype
// (flag in ws[0]; 1 = fp32, 0 = bf16). Intermediates are fp32.
// Batch processed in slices of NB chosen from ws_size (12 MB per batch elem).

DEV float ldin(const void* p, size_t i, int f) {
  return f ? reinterpret_cast<const float*>(p)[i]
           : __bfloat162float(reinterpret_cast<const bf16*>(p)[i]);
}

DEV float wave_max(float v) {
#pragma unroll
  for (int off = 32; off > 0; off >>= 1) v = fmaxf(v, __shfl_xor(v, off));
  return v;
}
DEV float wave_sum(float v) {
#pragma unroll
  for (int off = 32; off > 0; off >>= 1) v += __shfl_xor(v, off);
  return v;
}

// ---------------------------------------------------------------------------
// Dtype probe: fp32 data's low mantissa halves show exp-field 0x00/0xFF at
// ~0.8%; valid bf16 N(0,1) data never does. flag=1 -> fp32.
__global__ __launch_bounds__(256) void probe_dtype(const unsigned short* __restrict__ x,
                                                   int* __restrict__ flag) {
  __shared__ int cnt;
  if (threadIdx.x == 0) cnt = 0;
  __syncthreads();
  int c = 0;
  for (int i = threadIdx.x; i < 8192; i += 256) {
    int e = (x[i] >> 7) & 0xFF;
    if (e == 0xFF || e == 0x00) ++c;
  }
  atomicAdd(&cnt, c);
  __syncthreads();
  if (threadIdx.x == 0) flag[0] = (cnt >= 4) ? 1 : 0;
}

// ---------------------------------------------------------------------------
// GroupNorm statistics: one block per (local b, group). Writes mean, rstd.
template <bool EXT>
__global__ __launch_bounds__(256) void gn_stats(const void* __restrict__ x, size_t off,
                                                const int* __restrict__ dflag,
                                                float* __restrict__ stats,
                                                int cpg, int C, int N, int G) {
  int f = EXT ? dflag[0] : 1;
  int b = blockIdx.x / G;
  int g = blockIdx.x % G;
  size_t base = off + ((size_t)b * C + (size_t)g * cpg) * N;
  int count = cpg * N;
  float s = 0.f, ss = 0.f;
  for (int i = threadIdx.x; i < count; i += 256) {
    float v = ldin(x, base + i, f);
    s += v;
    ss += v * v;
  }
  s = wave_sum(s);
  ss = wave_sum(ss);
  __shared__ float r1[4], r2[4];
  int wid = threadIdx.x >> 6, lane = threadIdx.x & 63;
  if (lane == 0) { r1[wid] = s; r2[wid] = ss; }
  __syncthreads();
  if (threadIdx.x == 0) {
    s = r1[0] + r1[1] + r1[2] + r1[3];
    ss = r2[0] + r2[1] + r2[2] + r2[3];
    float mean = s / (float)count;
    float var = ss / (float)count - mean * mean;
    stats[blockIdx.x * 2 + 0] = mean;
    stats[blockIdx.x * 2 + 1] = rsqrtf(fmaxf(var, 0.f) + 1e-5f);
  }
}

// per-(b,c) affine:  y = x*s + t  implementing (x-mu)*rstd*gamma + beta
__global__ __launch_bounds__(256) void make_affine(const float* __restrict__ stats,
                                                   const void* __restrict__ gamma,
                                                   const void* __restrict__ beta,
                                                   const int* __restrict__ dflag,
                                                   float* __restrict__ sA, float* __restrict__ tA,
                                                   int C, int cpg, int total) {
  int f = dflag[0];
  int i = blockIdx.x * blockDim.x + threadIdx.x;
  if (i >= total) return;
  int b = i / C, c = i % C;
  int G = C / cpg;
  int g = c / cpg;
  float mean = stats[(b * G + g) * 2 + 0];
  float rstd = stats[(b * G + g) * 2 + 1];
  float gm = ldin(gamma, c, f);
  float bt = ldin(beta, c, f);
  sA[i] = rstd * gm;
  tA[i] = bt - mean * rstd * gm;
}

// ---------------------------------------------------------------------------
// Channel-major projection GEMM:
//   out[b,o,n] = sum_c W[o,c] * in(b,c,n) (+bias[o]) (+res_scale*res[b,o,n])
// in layout [B,C,N] (IN_SEQ: [B,N,C]). External tensors use runtime dtype flag.
// RES_T: 0=none, 1=internal fp32, 2=external (flagged).
template <bool IN_EXT, bool IN_SEQ, bool AFFINE, bool BIAS, int RES_T, bool OUT_EXT>
__global__ __launch_bounds__(256) void gemm_conv(
    const void* __restrict__ W, const void* __restrict__ in_, size_t in_off,
    const int* __restrict__ dflag,
    const float* __restrict__ sA, const float* __restrict__ tA,
    const void* __restrict__ bias,
    const void* __restrict__ res_, size_t res_off, float res_scale,
    void* __restrict__ out_, size_t out_off, int O, int C, int N) {
  int f = dflag[0];
  __shared__ float ws[16][65];
  __shared__ float xs[16][65];
  const int b = blockIdx.z;
  const int o0 = blockIdx.y * 64;
  const int n0 = blockIdx.x * 64;
  const int tx = threadIdx.x, ty = threadIdx.y;
  const int tid = ty * 16 + tx;
  float acc[4][4] = {};

  for (int c0 = 0; c0 < C; c0 += 16) {
    {  // W tile: 64 o x 16 c (weights always external -> flagged)
      int o_l = tid >> 2;
      int c_l = (tid & 3) << 2;
      size_t wp = (size_t)(o0 + o_l) * C + c0 + c_l;
#pragma unroll
      for (int j = 0; j < 4; ++j) ws[c_l + j][o_l] = ldin(W, wp + j, f);
    }
    if (!IN_SEQ) {  // X tile: 16 c x 64 n, coalesced along n
      int c_l = tid >> 6;
      int n_l = tid & 63;
#pragma unroll
      for (int k = 0; k < 4; ++k) {
        int c = c_l + (k << 2);
        size_t idx = ((size_t)b * C + c0 + c) * N + n0 + n_l;
        float v = IN_EXT ? ldin(in_, in_off + idx, f)
                         : reinterpret_cast<const float*>(in_)[idx];
        if (AFFINE) {
          int ai = b * C + c0 + c;
          v = v * sA[ai] + tA[ai];
        }
        xs[c][n_l] = v;
      }
    } else {  // context layout [B,N,C]
      int c_l = tid & 15;
      int n_b = tid >> 4;
#pragma unroll
      for (int k = 0; k < 4; ++k) {
        int n = n_b + (k << 4);
        float v = 0.f;
        if (n0 + n < N) {
          size_t idx = ((size_t)b * N + n0 + n) * C + c0 + c_l;
          v = IN_EXT ? ldin(in_, in_off + idx, f)
                     : reinterpret_cast<const float*>(in_)[idx];
        }
        xs[c_l][n] = v;
      }
    }
    __syncthreads();
#pragma unroll
    for (int cc = 0; cc < 16; ++cc) {
      float a[4], bb[4];
#pragma unroll
      for (int i = 0; i < 4; ++i) a[i] = ws[cc][ty + 16 * i];
#pragma unroll
      for (int j = 0; j < 4; ++j) bb[j] = xs[cc][tx + 16 * j];
#pragma unroll
      for (int i = 0; i < 4; ++i)
#pragma unroll
        for (int j = 0; j < 4; ++j) acc[i][j] = fmaf(a[i], bb[j], acc[i][j]);
    }
    __syncthreads();
  }
#pragma unroll
  for (int i = 0; i < 4; ++i) {
    int o = o0 + ty + 16 * i;
    float bv = BIAS ? ldin(bias, o, f) : 0.f;
#pragma unroll
    for (int j = 0; j < 4; ++j) {
      int n = n0 + tx + 16 * j;
      if (IN_SEQ && n >= N) continue;
      size_t oidx = ((size_t)b * O + o) * N + n;
      float v = acc[i][j] + bv;
      if (RES_T == 1) v += res_scale * reinterpret_cast<const float*>(res_)[oidx];
      if (RES_T == 2) v += res_scale * ldin(res_, res_off + oidx, f);
      if (OUT_EXT) {
        if (f)
          reinterpret_cast<float*>(out_)[out_off + oidx] = v;
        else
          reinterpret_cast<bf16*>(out_)[out_off + oidx] = __float2bfloat16(v);
      } else {
        reinterpret_cast<float*>(out_)[oidx] = v;
      }
    }
  }
}

// ---------------------------------------------------------------------------
// Self-attn scores: sim[b,i,j] = scale * sum_c q[b,c,i]*k[b,c,j]   (fp32 internal)
__global__ __launch_bounds__(256) void qk_sim(const float* __restrict__ q,
                                              const float* __restrict__ k,
                                              float* __restrict__ sim, float scale,
                                              int C, int N) {
  __shared__ float qs[16][65];
  __shared__ float ks[16][65];
  const int b = blockIdx.z;
  const int i0 = blockIdx.y * 64;
  const int j0 = blockIdx.x * 64;
  const int tx = threadIdx.x, ty = threadIdx.y;
  const int tid = ty * 16 + tx;
  const float* qb = q + (size_t)b * C * N;
  const float* kb = k + (size_t)b * C * N;
  float acc[4][4] = {};
  for (int c0 = 0; c0 < C; c0 += 16) {
    int c_l = tid >> 6;
    int e = tid & 63;
#pragma unroll
    for (int kk = 0; kk < 4; ++kk) {
      int c = c_l + (kk << 2);
      qs[c][e] = qb[(size_t)(c0 + c) * N + i0 + e];
      ks[c][e] = kb[(size_t)(c0 + c) * N + j0 + e];
    }
    __syncthreads();
#pragma unroll
    for (int cc = 0; cc < 16; ++cc) {
      float a[4], bb[4];
#pragma unroll
      for (int i = 0; i < 4; ++i) a[i] = qs[cc][ty + 16 * i];
#pragma unroll
      for (int j = 0; j < 4; ++j) bb[j] = ks[cc][tx + 16 * j];
#pragma unroll
      for (int i = 0; i < 4; ++i)
#pragma unroll
        for (int j = 0; j < 4; ++j) acc[i][j] = fmaf(a[i], bb[j], acc[i][j]);
    }
    __syncthreads();
  }
#pragma unroll
  for (int i = 0; i < 4; ++i)
#pragma unroll
    for (int j = 0; j < 4; ++j)
      sim[((size_t)b * N + i0 + ty + 16 * i) * N + j0 + tx + 16 * j] = acc[i][j] * scale;
}

// Softmax over rows of 1024 (in place)
__global__ __launch_bounds__(256) void softmax1024(float* __restrict__ sim) {
  float* row = sim + (size_t)blockIdx.x * 1024;
  int t = threadIdx.x;
  float4 v = reinterpret_cast<float4*>(row)[t];
  float m = fmaxf(fmaxf(v.x, v.y), fmaxf(v.z, v.w));
  m = wave_max(m);
  __shared__ float red[4];
  __shared__ float red2[4];
  int wid = t >> 6, lane = t & 63;
  if (lane == 0) red[wid] = m;
  __syncthreads();
  m = fmaxf(fmaxf(red[0], red[1]), fmaxf(red[2], red[3]));
  v.x = __expf(v.x - m);
  v.y = __expf(v.y - m);
  v.z = __expf(v.z - m);
  v.w = __expf(v.w - m);
  float s = v.x + v.y + v.z + v.w;
  s = wave_sum(s);
  if (lane == 0) red2[wid] = s;
  __syncthreads();
  s = red2[0] + red2[1] + red2[2] + red2[3];
  float inv = 1.f / s;
  v.x *= inv; v.y *= inv; v.z *= inv; v.w *= inv;
  reinterpret_cast<float4*>(row)[t] = v;
}

// o[b,c,i] = sum_j v[b,c,j] * p[b,i,j]
__global__ __launch_bounds__(256) void av_gemm(const float* __restrict__ v,
                                               const float* __restrict__ p,
                                               float* __restrict__ out, int C, int N) {
  __shared__ float vs[16][65];
  __shared__ float ps[16][65];
  const int b = blockIdx.z;
  const int c0 = blockIdx.y * 64;
  const int i0 = blockIdx.x * 64;
  const int tx = threadIdx.x, ty = threadIdx.y;
  const int tid = ty * 16 + tx;
  float acc[4][4] = {};
  for (int j0 = 0; j0 < N; j0 += 16) {
    int r = tid >> 4;
    int jl = tid & 15;
#pragma unroll
    for (int kk = 0; kk < 4; ++kk) {
      vs[jl][r + 16 * kk] = v[((size_t)b * C + c0 + r + 16 * kk) * N + j0 + jl];
      ps[jl][r + 16 * kk] = p[((size_t)b * N + i0 + r + 16 * kk) * N + j0 + jl];
    }
    __syncthreads();
#pragma unroll
    for (int jj = 0; jj < 16; ++jj) {
      float a[4], bb[4];
#pragma unroll
      for (int ci = 0; ci < 4; ++ci) a[ci] = vs[jj][ty + 16 * ci];
#pragma unroll
      for (int ii = 0; ii < 4; ++ii) bb[ii] = ps[jj][tx + 16 * ii];
#pragma unroll
      for (int ci = 0; ci < 4; ++ci)
#pragma unroll
        for (int ii = 0; ii < 4; ++ii) acc[ci][ii] = fmaf(a[ci], bb[ii], acc[ci][ii]);
    }
    __syncthreads();
  }
#pragma unroll
  for (int ci = 0; ci < 4; ++ci)
#pragma unroll
    for (int ii = 0; ii < 4; ++ii)
      out[((size_t)b * C + c0 + ty + 16 * ci) * N + i0 + tx + 16 * ii] = acc[ci][ii];
}

// ---------------------------------------------------------------------------
// Cross-attn scores: sim2[b,h,i,j] = 0.125 * sum_{c<64} q[b,h*64+c,i]*k2[b,h*64+c,j]
__global__ __launch_bounds__(256) void cross_sim(const float* __restrict__ q,
                                                 const float* __restrict__ k2,
                                                 float* __restrict__ sim2, int N, int M) {
  __shared__ float qs[16][65];
  __shared__ float ks[16][80];
  const int b = blockIdx.z;
  const int h = blockIdx.y;
  const int i0 = blockIdx.x * 64;
  const int tx = threadIdx.x, ty = threadIdx.y;
  const int tid = ty * 16 + tx;
  const float* qb = q + ((size_t)b * 512 + h * 64) * N;
  const float* kb = k2 + ((size_t)b * 512 + h * 64) * M;
  float acc[4][5] = {};
  for (int c0 = 0; c0 < 64; c0 += 16) {
    int c_l = tid >> 6;
    int e = tid & 63;
#pragma unroll
    for (int kk = 0; kk < 4; ++kk) {
      int c = c_l + (kk << 2);
      qs[c][e] = qb[(size_t)(c0 + c) * N + i0 + e];
    }
    for (int idx = tid; idx < 16 * 80; idx += 256) {
      int cc = idx / 80, j = idx % 80;
      ks[cc][j] = (j < M) ? kb[(size_t)(c0 + cc) * M + j] : 0.f;
    }
    __syncthreads();
#pragma unroll
    for (int cc = 0; cc < 16; ++cc) {
      float a[4];
#pragma unroll
      for (int ii = 0; ii < 4; ++ii) a[ii] = qs[cc][ty + 16 * ii];
#pragma unroll
      for (int jj = 0; jj < 5; ++jj) {
        float bb = ks[cc][tx + 16 * jj];
#pragma unroll
        for (int ii = 0; ii < 4; ++ii) acc[ii][jj] = fmaf(a[ii], bb, acc[ii][jj]);
      }
    }
    __syncthreads();
  }
#pragma unroll
  for (int ii = 0; ii < 4; ++ii)
#pragma unroll
    for (int jj = 0; jj < 5; ++jj) {
      int j = tx + 16 * jj;
      if (j < M)
        sim2[(((size_t)b * 8 + h) * N + i0 + ty + 16 * ii) * M + j] = acc[ii][jj] * 0.125f;
    }
}

// softmax over rows of 77 (one wave per row)
__global__ __launch_bounds__(64) void softmax77(float* __restrict__ sim2) {
  float* row = sim2 + (size_t)blockIdx.x * 77;
  int l = threadIdx.x;
  float v0 = row[l];
  float v1 = (l < 13) ? row[64 + l] : -1e30f;
  float m = wave_max(fmaxf(v0, v1));
  float e0 = __expf(v0 - m);
  float e1 = (l < 13) ? __expf(v1 - m) : 0.f;
  float s = wave_sum(e0 + e1);
  float inv = 1.f / s;
  row[l] = e0 * inv;
  if (l < 13) row[64 + l] = e1 * inv;
}

// o[b, h*64+c, i] = sum_j p2[b,h,i,j] * v2[b,h*64+c,j]
__global__ __launch_bounds__(256) void cross_av(const float* __restrict__ p2,
                                                const float* __restrict__ v2,
                                                float* __restrict__ out, int N, int M) {
  __shared__ float ps[64][81];
  __shared__ float vs[64][81];
  const int b = blockIdx.z;
  const int h = blockIdx.y;
  const int i0 = blockIdx.x * 64;
  const int tx = threadIdx.x, ty = threadIdx.y;
  const int tid = ty * 16 + tx;
  for (int idx = tid; idx < 64 * 80; idx += 256) {
    int r = idx / 80, c = idx % 80;
    vs[r][c] = (c < M) ? v2[((size_t)b * 512 + h * 64 + r) * M + c] : 0.f;
    ps[r][c] = (c < M) ? p2[(((size_t)b * 8 + h) * N + i0 + r) * M + c] : 0.f;
  }
  __syncthreads();
  float acc[4][4] = {};
  for (int j = 0; j < M; ++j) {
    float a[4], bb[4];
#pragma unroll
    for (int ci = 0; ci < 4; ++ci) a[ci] = vs[ty + 16 * ci][j];
#pragma unroll
    for (int ii = 0; ii < 4; ++ii) bb[ii] = ps[tx + 16 * ii][j];
#pragma unroll
    for (int ci = 0; ci < 4; ++ci)
#pragma unroll
      for (int ii = 0; ii < 4; ++ii) acc[ci][ii] = fmaf(a[ci], bb[ii], acc[ci][ii]);
  }
#pragma unroll
  for (int ci = 0; ci < 4; ++ci)
#pragma unroll
    for (int ii = 0; ii < 4; ++ii)
      out[((size_t)b * 512 + h * 64 + ty + 16 * ci) * N + i0 + tx + 16 * ii] = acc[ci][ii];
}

// ---------------------------------------------------------------------------
extern "C" void kernel_launch(void* const* d_in, const int* in_sizes, int n_in,
                              void* d_out, int out_size, void* d_ws, size_t ws_size,
                              hipStream_t stream) {
  const void* x       = d_in[0];
  const void* ctx     = d_in[1];
  const void* gn1_g   = d_in[2];
  const void* gn1_b   = d_in[3];
  const void* w_in    = d_in[4];
  const void* b_in    = d_in[5];
  const void* sa_wk   = d_in[6];
  const void* sa_wq   = d_in[7];
  const void* sa_wv   = d_in[8];
  const void* sa_wp   = d_in[9];
  const void* sa_gn_g = d_in[10];
  const void* sa_gn_b = d_in[11];
  const void* ca_wq   = d_in[12];
  const void* ca_wk   = d_in[13];
  const void* ca_wv   = d_in[14];
  const void* ca_wo   = d_in[15];
  const void* ca_bo   = d_in[16];
  const void* w_out   = d_in[17];
  const void* b_out   = d_in[18];

  const int B = 16, CIN = 256, N = 1024, INNER = 512, M = 77, CTXD = 768;

  // Pick largest batch slice NB with footprint <= ws_size.
  // footprint(NB) = (32768 + NB*3,145,728) floats.
  int NB = 16;
  while (NB > 1 && (32768ull + (size_t)NB * 3145728ull) * 4ull > ws_size) NB >>= 1;

  float* wsf = reinterpret_cast<float*>(d_ws);
  int* flagp = reinterpret_cast<int*>(d_ws);
  float* SM = wsf + 64;
  float* stats1 = SM;            // <=1024
  float* stats2 = SM + 1024;     // <=1024
  float* s1 = SM + 2048;         // <=4096
  float* t1 = SM + 6144;         // <=4096
  float* s2 = SM + 10240;        // <=8192
  float* t2 = SM + 18432;        // <=8192 (ends 26624 < 32768)
  float* big = wsf + 32768;
  size_t szH = (size_t)NB * 512 * 1024;  // one [NB,512,1024] fp32 buffer
  float* A  = big;            // h1
  float* Bq = A + szH;        // q -> self o -> cross o
  float* Ck = Bq + szH;       // k -> h2
  float* Dv = Ck + szH;       // v -> cross q -> h3
  float* S  = Dv + szH;       // sim [NB,N,N]; later overlaid:
  float* k2b  = S;                             // [NB,512,77]
  float* v2b  = S + (size_t)NB * 65536;        // [NB,512,77]
  float* sim2 = S + (size_t)NB * 131072;       // [NB,8,N,77]

  dim3 blk(16, 16);

  // dtype probe (writes flag used by all external-tensor loads)
  probe_dtype<<<1, 256, 0, stream>>>((const unsigned short*)x, flagp);

  for (int b0 = 0; b0 < B; b0 += NB) {
    size_t xoff = (size_t)b0 * CIN * N;   // element offsets into external tensors
    size_t coff = (size_t)b0 * M * CTXD;

    // 1) GroupNorm1 stats + affine
    gn_stats<true><<<NB * 32, 256, 0, stream>>>(x, xoff, flagp, stats1, 8, CIN, N, 32);
    make_affine<<<(NB * CIN + 255) / 256, 256, 0, stream>>>(stats1, gn1_g, gn1_b, flagp, s1, t1, CIN, 8, NB * CIN);

    // 2) conv_in: h1 = w_in @ gn1(x) + b_in -> A
    gemm_conv<true, false, true, true, 0, false><<<dim3(16, 8, NB), blk, 0, stream>>>(
        w_in, x, xoff, flagp, s1, t1, b_in, nullptr, 0, 0.f, A, 0, INNER, CIN, N);

    // 3) GroupNorm2 stats + affine
    gn_stats<false><<<NB * 32, 256, 0, stream>>>(A, 0, flagp, stats2, 16, INNER, N, 32);
    make_affine<<<(NB * INNER + 255) / 256, 256, 0, stream>>>(stats2, sa_gn_g, sa_gn_b, flagp, s2, t2, INNER, 16, NB * INNER);

    // 4) self-attn q,k,v
    gemm_conv<false, false, true, false, 0, false><<<dim3(16, 8, NB), blk, 0, stream>>>(
        sa_wq, A, 0, flagp, s2, t2, nullptr, nullptr, 0, 0.f, Bq, 0, INNER, INNER, N);
    gemm_conv<false, false, true, false, 0, false><<<dim3(16, 8, NB), blk, 0, stream>>>(
        sa_wk, A, 0, flagp, s2, t2, nullptr, nullptr, 0, 0.f, Ck, 0, INNER, INNER, N);
    gemm_conv<false, false, true, false, 0, false><<<dim3(16, 8, NB), blk, 0, stream>>>(
        sa_wv, A, 0, flagp, s2, t2, nullptr, nullptr, 0, 0.f, Dv, 0, INNER, INNER, N);

    // 5) scores + softmax + o (o overwrites q slot Bq)
    qk_sim<<<dim3(16, 16, NB), blk, 0, stream>>>(Bq, Ck, S, 1.0f / sqrtf(512.f), INNER, N);
    softmax1024<<<NB * N, 256, 0, stream>>>(S);
    av_gemm<<<dim3(16, 8, NB), blk, 0, stream>>>(Dv, S, Bq, INNER, N);

    // 6) proj + residual: h2 = wp @ o + 2*h1 -> Ck
    gemm_conv<false, false, false, false, 1, false><<<dim3(16, 8, NB), blk, 0, stream>>>(
        sa_wp, Bq, 0, flagp, nullptr, nullptr, nullptr, A, 0, 2.0f, Ck, 0, INNER, INNER, N);

    // 7) cross-attn q from h2 -> Dv
    gemm_conv<false, false, false, false, 0, false><<<dim3(16, 8, NB), blk, 0, stream>>>(
        ca_wq, Ck, 0, flagp, nullptr, nullptr, nullptr, nullptr, 0, 0.f, Dv, 0, INNER, INNER, N);

    // 8) cross k,v from context [NB,77,768] (overlay on dead S region)
    gemm_conv<true, true, false, false, 0, false><<<dim3(2, 8, NB), blk, 0, stream>>>(
        ca_wk, ctx, coff, flagp, nullptr, nullptr, nullptr, nullptr, 0, 0.f, k2b, 0, INNER, CTXD, M);
    gemm_conv<true, true, false, false, 0, false><<<dim3(2, 8, NB), blk, 0, stream>>>(
        ca_wv, ctx, coff, flagp, nullptr, nullptr, nullptr, nullptr, 0, 0.f, v2b, 0, INNER, CTXD, M);

    // 9) cross scores + softmax + o (o overwrites Bq)
    cross_sim<<<dim3(16, 8, NB), blk, 0, stream>>>(Dv, k2b, sim2, N, M);
    softmax77<<<NB * 8 * N, 64, 0, stream>>>(sim2);
    cross_av<<<dim3(16, 8, NB), blk, 0, stream>>>(sim2, v2b, Bq, N, M);

    // 10) wo + bias + residual: h3 = wo @ o + bo + h2 -> Dv
    gemm_conv<false, false, false, true, 1, false><<<dim3(16, 8, NB), blk, 0, stream>>>(
        ca_wo, Bq, 0, flagp, nullptr, nullptr, ca_bo, Ck, 0, 1.0f, Dv, 0, INNER, INNER, N);

    // 11) conv_out + b_out + input residual (dtype-flagged external out)
    gemm_conv<false, false, false, true, 2, true><<<dim3(16, 4, NB), blk, 0, stream>>>(
        w_out, Dv, 0, flagp, nullptr, nullptr, b_out, x, xoff, 1.0f, d_out, xoff, CIN, INNER, N);
  }

  (void)in_sizes; (void)n_in; (void)out_size;
}

// Round 4
// 1118.719 us; speedup vs baseline: 2.0581x; 2.0581x over previous
//
#include <hip/hip_runtime.h>
#include <math.h>

#define DEV __device__ __forceinline__

using f32x4 = __attribute__((ext_vector_type(4))) float;
using bf8   = __attribute__((ext_vector_type(8))) short;
using bf4   = __attribute__((ext_vector_type(4))) short;

// B=16, CIN=256, N=1024, INNER=512, CTX_N=77, CTX_D=768, HEADS=8, DH=64.
// Activations sequence-major [n][c] bf16 so every GEMM is C=A*B^T with K
// contiguous for both operands -> one generic MFMA kernel (16x16x32 bf16).

DEV short f2b(float x) {
  unsigned u = __builtin_bit_cast(unsigned, x);
  u += 0x7FFFu + ((u >> 16) & 1u);
  return (short)(u >> 16);
}
DEV float b2f(short s) {
  unsigned u = ((unsigned)(unsigned short)s) << 16;
  return __builtin_bit_cast(float, u);
}
DEV float ldin(const void* p, size_t i, int f) {
  return f ? reinterpret_cast<const float*>(p)[i]
           : b2f(reinterpret_cast<const short*>(p)[i]);
}

DEV float wave_max(float v) {
#pragma unroll
  for (int off = 32; off > 0; off >>= 1) v = fmaxf(v, __shfl_xor(v, off));
  return v;
}
DEV float wave_sum(float v) {
#pragma unroll
  for (int off = 32; off > 0; off >>= 1) v += __shfl_xor(v, off);
  return v;
}

// ---------------------------------------------------------------------------
// Dtype probe: fp32 data's low mantissa halves show exp-field 0x00/0xFF often;
// valid bf16 N(0,1) data never does. flag=1 -> fp32.
__global__ __launch_bounds__(256) void probe_dtype(const unsigned short* __restrict__ x,
                                                   int* __restrict__ flag) {
  __shared__ int cnt;
  if (threadIdx.x == 0) cnt = 0;
  __syncthreads();
  int c = 0;
  for (int i = threadIdx.x; i < 8192; i += 256) {
    int e = (x[i] >> 7) & 0xFF;
    if (e == 0xFF || e == 0x00) ++c;
  }
  atomicAdd(&cnt, c);
  __syncthreads();
  if (threadIdx.x == 0) flag[0] = (cnt >= 4) ? 1 : 0;
}

// ---------------------------------------------------------------------------
// GN1 stats on external x [b][C][N] channel-major (group = contiguous block).
__global__ __launch_bounds__(256) void gn_stats_ext(const void* __restrict__ x, size_t off,
                                                    const int* __restrict__ dflag,
                                                    float* __restrict__ stats,
                                                    int cpg, int C, int N, int G) {
  int f = dflag[0];
  int b = blockIdx.x / G;
  int g = blockIdx.x % G;
  size_t base = off + ((size_t)b * C + (size_t)g * cpg) * N;
  int count = cpg * N;
  float s = 0.f, ss = 0.f;
  for (int i = threadIdx.x; i < count; i += 256) {
    float v = ldin(x, base + i, f);
    s += v;
    ss += v * v;
  }
  s = wave_sum(s);
  ss = wave_sum(ss);
  __shared__ float r1[4], r2[4];
  int wid = threadIdx.x >> 6, lane = threadIdx.x & 63;
  if (lane == 0) { r1[wid] = s; r2[wid] = ss; }
  __syncthreads();
  if (threadIdx.x == 0) {
    s = r1[0] + r1[1] + r1[2] + r1[3];
    ss = r2[0] + r2[1] + r2[2] + r2[3];
    float mean = s / (float)count;
    float var = ss / (float)count - mean * mean;
    stats[blockIdx.x * 2 + 0] = mean;
    stats[blockIdx.x * 2 + 1] = rsqrtf(fmaxf(var, 0.f) + 1e-5f);
  }
}

// GN2 stats on internal bf16 h1 [b][1024][512] seq-major; group = 16 channels.
__global__ __launch_bounds__(256) void gn_stats2(const short* __restrict__ h1,
                                                 float* __restrict__ stats) {
  int b = blockIdx.x >> 5, g = blockIdx.x & 31;
  int cl = threadIdx.x & 15, nr = threadIdx.x >> 4;
  float s = 0.f, ss = 0.f;
  for (int n = nr; n < 1024; n += 16) {
    float v = b2f(h1[((size_t)b * 1024 + n) * 512 + g * 16 + cl]);
    s += v;
    ss += v * v;
  }
  s = wave_sum(s);
  ss = wave_sum(ss);
  __shared__ float r1[4], r2[4];
  int wid = threadIdx.x >> 6, lane = threadIdx.x & 63;
  if (lane == 0) { r1[wid] = s; r2[wid] = ss; }
  __syncthreads();
  if (threadIdx.x == 0) {
    s = r1[0] + r1[1] + r1[2] + r1[3];
    ss = r2[0] + r2[1] + r2[2] + r2[3];
    float mean = s / 16384.f;
    float var = ss / 16384.f - mean * mean;
    stats[blockIdx.x * 2 + 0] = mean;
    stats[blockIdx.x * 2 + 1] = rsqrtf(fmaxf(var, 0.f) + 1e-5f);
  }
}

// per-(b,c) affine coefficients
__global__ __launch_bounds__(256) void make_affine(const float* __restrict__ stats,
                                                   const void* __restrict__ gamma,
                                                   const void* __restrict__ beta,
                                                   const int* __restrict__ dflag,
                                                   float* __restrict__ sA, float* __restrict__ tA,
                                                   int C, int cpg, int total) {
  int f = dflag[0];
  int i = blockIdx.x * blockDim.x + threadIdx.x;
  if (i >= total) return;
  int b = i / C, c = i % C;
  int G = C / cpg;
  int g = c / cpg;
  float mean = stats[(b * G + g) * 2 + 0];
  float rstd = stats[(b * G + g) * 2 + 1];
  float gm = ldin(gamma, c, f);
  float bt = ldin(beta, c, f);
  sA[i] = rstd * gm;
  tA[i] = bt - mean * rstd * gm;
}

// ---------------------------------------------------------------------------
// x [b][256][1024] ext -> xT [b][1024][256] bf16 with GN1 affine.
__global__ __launch_bounds__(256) void transpose_affine(const void* __restrict__ x, size_t xoff,
                                                        const int* __restrict__ dflag,
                                                        const float* __restrict__ s1,
                                                        const float* __restrict__ t1,
                                                        short* __restrict__ xT) {
  int f = dflag[0];
  __shared__ short xs[64 * 264];
  int b = blockIdx.y, n0 = blockIdx.x * 64;
  int tid = threadIdx.x;
  for (int it = 0; it < 64; ++it) {
    int e = it * 256 + tid;
    int c = e >> 6, nl = e & 63;
    float v = ldin(x, xoff + ((size_t)b * 256 + c) * 1024 + n0 + nl, f);
    v = v * s1[b * 256 + c] + t1[b * 256 + c];
    xs[nl * 264 + c] = f2b(v);
  }
  __syncthreads();
  int nl = tid >> 2, cch = (tid & 3) * 64;
#pragma unroll
  for (int m = 0; m < 8; ++m)
    *(bf8*)&xT[((size_t)b * 1024 + n0 + nl) * 256 + cch + m * 8] =
        *(const bf8*)&xs[nl * 264 + cch + m * 8];
}

// h1 bf16 -> h1g bf16 with GN2 affine (per c).
__global__ __launch_bounds__(256) void affine_apply(const short* __restrict__ h1,
                                                    const float* __restrict__ s2,
                                                    const float* __restrict__ t2,
                                                    short* __restrict__ out) {
  size_t gid = (size_t)blockIdx.x * 256 + threadIdx.x;
  size_t base = gid * 4;
  int bl = (int)(base >> 19);
  int c = (int)(base & 511);
  bf4 v = *(const bf4*)&h1[base];
  bf4 o;
#pragma unroll
  for (int j = 0; j < 4; ++j)
    o[j] = f2b(b2f(v[j]) * s2[bl * 512 + c + j] + t2[bl * 512 + c + j]);
  *(bf4*)&out[base] = o;
}

// ---------------------------------------------------------------------------
// Generic MFMA GEMM: OUT[z][p][q] = scale * sum_k Bm[p][k]*Am[q][k] (+biases/res)
// q is the contiguous output dim. A-slot gets Am (q rows), B-slot gets Bm (p rows).
// D layout: col(lane&15)=p-local, row(quad*4+reg)=q-local -> 4-consecutive-q stores.
// A_EXT/B_EXT: operand dtype external(flagged) vs internal bf16.
// OUT_T: 0 bf16, 1 fp32, 2 external. RES_T: 0 none, 1 bf16, 2 external.
template <int A_EXT, int B_EXT, int OUT_T, int BIAS_P_, int BIAS_Q_, int RES_T>
__global__ __launch_bounds__(256) void mm(
    const void* __restrict__ Am, size_t aoff, int lda, size_t zsa,
    const void* __restrict__ Bm, size_t boff, int ldb, size_t zsb,
    void* __restrict__ Out, size_t ooff, int ldc, size_t zsc,
    const void* __restrict__ Res, size_t roff, size_t zsr, float res_scale,
    const void* __restrict__ biasP, const void* __restrict__ biasQ,
    const int* __restrict__ dflag, float scale, int P, int K) {
  const int f = dflag[0];
  __shared__ short lA[128 * 40];
  __shared__ short lB[128 * 40];
  const int tid = threadIdx.x;
  const int z = blockIdx.z;
  const int q0 = blockIdx.x * 128, p0 = blockIdx.y * 128;
  const int l = tid & 63;
  const int w = tid >> 6;
  const int wq = (w & 1) * 64, wp = (w >> 1) * 64;
  const int lm = l & 15, quad = l >> 4;
  const int sr = tid >> 1;
  const int sc = (tid & 1) << 4;
  const size_t abase = aoff + (size_t)z * zsa + (size_t)(q0 + sr) * lda + sc;
  const size_t bbase = boff + (size_t)z * zsb + (size_t)(p0 + sr) * ldb + sc;
  const bool bvalid = (p0 + sr) < P;

  f32x4 acc[4][4];
#pragma unroll
  for (int i = 0; i < 4; ++i)
#pragma unroll
    for (int j = 0; j < 4; ++j) acc[i][j] = (f32x4){0.f, 0.f, 0.f, 0.f};

  for (int kk = 0; kk < K; kk += 32) {
    __syncthreads();
    short va[16], vb[16];
    {
      size_t g = abase + kk;
      if (A_EXT && f) {
        const float* p = reinterpret_cast<const float*>(Am);
#pragma unroll
        for (int i = 0; i < 16; i += 4) {
          float4 t4 = *(const float4*)&p[g + i];
          va[i] = f2b(t4.x); va[i + 1] = f2b(t4.y);
          va[i + 2] = f2b(t4.z); va[i + 3] = f2b(t4.w);
        }
      } else {
        const short* p = reinterpret_cast<const short*>(Am);
        *(bf8*)&va[0] = *(const bf8*)&p[g];
        *(bf8*)&va[8] = *(const bf8*)&p[g + 8];
      }
    }
    if (bvalid) {
      size_t g = bbase + kk;
      if (B_EXT && f) {
        const float* p = reinterpret_cast<const float*>(Bm);
#pragma unroll
        for (int i = 0; i < 16; i += 4) {
          float4 t4 = *(const float4*)&p[g + i];
          vb[i] = f2b(t4.x); vb[i + 1] = f2b(t4.y);
          vb[i + 2] = f2b(t4.z); vb[i + 3] = f2b(t4.w);
        }
      } else {
        const short* p = reinterpret_cast<const short*>(Bm);
        *(bf8*)&vb[0] = *(const bf8*)&p[g];
        *(bf8*)&vb[8] = *(const bf8*)&p[g + 8];
      }
    } else {
#pragma unroll
      for (int i = 0; i < 16; ++i) vb[i] = 0;
    }
    *(bf8*)&lA[sr * 40 + sc] = *(bf8*)&va[0];
    *(bf8*)&lA[sr * 40 + sc + 8] = *(bf8*)&va[8];
    *(bf8*)&lB[sr * 40 + sc] = *(bf8*)&vb[0];
    *(bf8*)&lB[sr * 40 + sc + 8] = *(bf8*)&vb[8];
    __syncthreads();

    bf8 af[4], bfr[4];
#pragma unroll
    for (int i = 0; i < 4; ++i)
      af[i] = *(const bf8*)&lA[(wq + i * 16 + lm) * 40 + quad * 8];
#pragma unroll
    for (int i = 0; i < 4; ++i)
      bfr[i] = *(const bf8*)&lB[(wp + i * 16 + lm) * 40 + quad * 8];
#pragma unroll
    for (int qi = 0; qi < 4; ++qi)
#pragma unroll
      for (int pi = 0; pi < 4; ++pi)
        acc[qi][pi] = __builtin_amdgcn_mfma_f32_16x16x32_bf16(af[qi], bfr[pi], acc[qi][pi], 0, 0, 0);
  }

  const size_t obase = ooff + (size_t)z * zsc;
#pragma unroll
  for (int pi = 0; pi < 4; ++pi) {
    int p = p0 + wp + pi * 16 + lm;
    if (p >= P) continue;
    float bp = BIAS_P_ ? ldin(biasP, p, f) : 0.f;
#pragma unroll
    for (int qi = 0; qi < 4; ++qi) {
      int q = q0 + wq + qi * 16 + quad * 4;
      f32x4 d = acc[qi][pi];
      float v[4];
#pragma unroll
      for (int r = 0; r < 4; ++r) {
        v[r] = d[r] * scale + bp;
        if (BIAS_Q_) v[r] += ldin(biasQ, q + r, f);
      }
      if (RES_T == 1) {
        bf4 rv = *(const bf4*)&reinterpret_cast<const short*>(Res)[roff + (size_t)z * zsr + (size_t)p * ldc + q];
#pragma unroll
        for (int r = 0; r < 4; ++r) v[r] += res_scale * b2f(rv[r]);
      } else if (RES_T == 2) {
        size_t ri = roff + (size_t)z * zsr + (size_t)p * ldc + q;
        if (f) {
          float4 rf = *(const float4*)&reinterpret_cast<const float*>(Res)[ri];
          v[0] += res_scale * rf.x; v[1] += res_scale * rf.y;
          v[2] += res_scale * rf.z; v[3] += res_scale * rf.w;
        } else {
          bf4 rv = *(const bf4*)&reinterpret_cast<const short*>(Res)[ri];
#pragma unroll
          for (int r = 0; r < 4; ++r) v[r] += res_scale * b2f(rv[r]);
        }
      }
      size_t idx = obase + (size_t)p * ldc + q;
      if (OUT_T == 0) {
        bf4 o;
#pragma unroll
        for (int r = 0; r < 4; ++r) o[r] = f2b(v[r]);
        *(bf4*)&reinterpret_cast<short*>(Out)[idx] = o;
      } else if (OUT_T == 1) {
        f32x4 o = {v[0], v[1], v[2], v[3]};
        *(f32x4*)&reinterpret_cast<float*>(Out)[idx] = o;
      } else {
        if (f) {
          f32x4 o = {v[0], v[1], v[2], v[3]};
          *(f32x4*)&reinterpret_cast<float*>(Out)[idx] = o;
        } else {
          bf4 o;
#pragma unroll
          for (int r = 0; r < 4; ++r) o[r] = f2b(v[r]);
          *(bf4*)&reinterpret_cast<short*>(Out)[idx] = o;
        }
      }
    }
  }
}

// ---------------------------------------------------------------------------
// Softmax over rows of 1024: fp32 sim in, bf16 P out.
__global__ __launch_bounds__(256) void softmax1024(const float* __restrict__ sim,
                                                   short* __restrict__ P) {
  const float* row = sim + (size_t)blockIdx.x * 1024;
  int t = threadIdx.x;
  float4 v = ((const float4*)row)[t];
  float m = fmaxf(fmaxf(v.x, v.y), fmaxf(v.z, v.w));
  m = wave_max(m);
  __shared__ float red[4], red2[4];
  int wid = t >> 6, lane = t & 63;
  if (lane == 0) red[wid] = m;
  __syncthreads();
  m = fmaxf(fmaxf(red[0], red[1]), fmaxf(red[2], red[3]));
  v.x = __expf(v.x - m); v.y = __expf(v.y - m);
  v.z = __expf(v.z - m); v.w = __expf(v.w - m);
  float s = v.x + v.y + v.z + v.w;
  s = wave_sum(s);
  if (lane == 0) red2[wid] = s;
  __syncthreads();
  s = red2[0] + red2[1] + red2[2] + red2[3];
  float inv = 1.f / s;
  bf4 o;
  o[0] = f2b(v.x * inv); o[1] = f2b(v.y * inv);
  o[2] = f2b(v.z * inv); o[3] = f2b(v.w * inv);
  ((bf4*)(P + (size_t)blockIdx.x * 1024))[t] = o;
}

// ---------------------------------------------------------------------------
// Cross-attn scores + softmax fused: P2[b,h,i,j] over j<77. q2,k2 bf16.
__global__ __launch_bounds__(256) void cross_sim_sm(const short* __restrict__ q2,
                                                    const short* __restrict__ k2,
                                                    short* __restrict__ P2) {
  __shared__ float ks[77][65];
  __shared__ float qs[32][65];
  const int b = blockIdx.z, h = blockIdx.y, i0 = blockIdx.x * 32;
  const int tid = threadIdx.x;
  for (int idx = tid; idx < 77 * 64; idx += 256) {
    int j = idx >> 6, d = idx & 63;
    ks[j][d] = b2f(k2[(size_t)b * 39424 + j * 512 + h * 64 + d]);
  }
  for (int idx = tid; idx < 32 * 64; idx += 256) {
    int il = idx >> 6, d = idx & 63;
    qs[il][d] = b2f(q2[((size_t)b * 1024 + i0 + il) * 512 + h * 64 + d]);
  }
  __syncthreads();
  int il = tid >> 3, jg = tid & 7;
  float ev[10];
  float mx = -1e30f;
#pragma unroll
  for (int jj = 0; jj < 10; ++jj) {
    int j = jg + jj * 8;
    float a = -1e30f;
    if (j < 77) {
      a = 0.f;
#pragma unroll
      for (int d = 0; d < 64; ++d) a = fmaf(qs[il][d], ks[j][d], a);
      a *= 0.125f;
    }
    ev[jj] = a;
    mx = fmaxf(mx, a);
  }
  mx = fmaxf(mx, __shfl_xor(mx, 1));
  mx = fmaxf(mx, __shfl_xor(mx, 2));
  mx = fmaxf(mx, __shfl_xor(mx, 4));
  float s = 0.f;
#pragma unroll
  for (int jj = 0; jj < 10; ++jj) {
    int j = jg + jj * 8;
    if (j < 77) { ev[jj] = __expf(ev[jj] - mx); s += ev[jj]; }
  }
  s += __shfl_xor(s, 1);
  s += __shfl_xor(s, 2);
  s += __shfl_xor(s, 4);
  float inv = 1.f / s;
#pragma unroll
  for (int jj = 0; jj < 10; ++jj) {
    int j = jg + jj * 8;
    if (j < 77)
      P2[(((size_t)b * 8 + h) * 1024 + i0 + il) * 77 + j] = f2b(ev[jj] * inv);
  }
}

// o2[b,i,h*64+c] = sum_{j<77} P2[b,h,i,j] * v2[b,j,h*64+c]
__global__ __launch_bounds__(256) void cross_av_k(const short* __restrict__ P2,
                                                  const short* __restrict__ v2,
                                                  short* __restrict__ o2) {
  __shared__ float vs[77][65];
  __shared__ float ps[32][80];
  const int b = blockIdx.z, h = blockIdx.y, i0 = blockIdx.x * 32;
  const int tid = threadIdx.x;
  for (int idx = tid; idx < 77 * 64; idx += 256) {
    int j = idx >> 6, c = idx & 63;
    vs[j][c] = b2f(v2[(size_t)b * 39424 + j * 512 + h * 64 + c]);
  }
  for (int idx = tid; idx < 32 * 77; idx += 256) {
    int il = idx / 77, j = idx - il * 77;
    ps[il][j] = b2f(P2[(((size_t)b * 8 + h) * 1024 + i0 + il) * 77 + j]);
  }
  __syncthreads();
  int il = tid >> 3, cg = tid & 7;
  float a[8] = {0.f, 0.f, 0.f, 0.f, 0.f, 0.f, 0.f, 0.f};
  for (int j = 0; j < 77; ++j) {
    float p = ps[il][j];
#pragma unroll
    for (int m = 0; m < 8; ++m) a[m] = fmaf(p, vs[j][cg + m * 8], a[m]);
  }
#pragma unroll
  for (int m = 0; m < 8; ++m)
    o2[((size_t)b * 1024 + i0 + il) * 512 + h * 64 + cg + m * 8] = f2b(a[m]);
}

// ---------------------------------------------------------------------------
extern "C" void kernel_launch(void* const* d_in, const int* in_sizes, int n_in,
                              void* d_out, int out_size, void* d_ws, size_t ws_size,
                              hipStream_t stream) {
  const void* x       = d_in[0];
  const void* ctx     = d_in[1];
  const void* gn1_g   = d_in[2];
  const void* gn1_b   = d_in[3];
  const void* w_in    = d_in[4];
  const void* b_in    = d_in[5];
  const void* sa_wk   = d_in[6];
  const void* sa_wq   = d_in[7];
  const void* sa_wv   = d_in[8];
  const void* sa_wp   = d_in[9];
  const void* sa_gn_g = d_in[10];
  const void* sa_gn_b = d_in[11];
  const void* ca_wq   = d_in[12];
  const void* ca_wk   = d_in[13];
  const void* ca_wv   = d_in[14];
  const void* ca_wo   = d_in[15];
  const void* ca_bo   = d_in[16];
  const void* w_out   = d_in[17];
  const void* b_out   = d_in[18];

  const int B = 16;
  // footprint = 128KB + NB * 11 MB
  int NB = 16;
  while (NB > 1 && 131072ull + (size_t)NB * 11534336ull > ws_size) NB >>= 1;

  char* base = reinterpret_cast<char*>(d_ws);
  int* flagp = reinterpret_cast<int*>(base);
  float* smf = reinterpret_cast<float*>(base + 1024);
  float* stats1 = smf;
  float* stats2 = smf + 1024;
  float* s1 = smf + 2048;
  float* t1 = smf + 6144;
  float* s2 = smf + 10240;
  float* t2 = smf + 18432;
  char* big = base + 131072;
  const size_t MB = 1048576;
  short* U0 = (short*)(big + 0 * (size_t)NB * MB);  // h1 -> h3
  short* U1 = (short*)(big + 1 * (size_t)NB * MB);  // h1g -> o_attn
  short* U2 = (short*)(big + 2 * (size_t)NB * MB);  // q -> q2
  short* U3 = (short*)(big + 3 * (size_t)NB * MB);  // k -> h2
  short* U4 = (short*)(big + 4 * (size_t)NB * MB);  // vT -> o2
  char* Sreg = big + 5 * (size_t)NB * MB;           // 6 MB/b region
  float* simb = (float*)Sreg;                          // [NB,1024,1024] fp32
  short* Pbuf = (short*)(Sreg + (size_t)NB * 4 * MB);  // [NB,1024,1024] bf16
  short* xT = (short*)Sreg;                            // [NB,1024,256] bf16 (pre-sim)
  short* k2 = (short*)Sreg;                            // [NB,77,512] bf16 (post-sim)
  short* v2 = (short*)(Sreg + (size_t)NB * 78848);
  short* P2 = (short*)(Sreg + (size_t)NB * 157696);    // [NB,8,1024,77] bf16

  probe_dtype<<<1, 256, 0, stream>>>((const unsigned short*)x, flagp);

  const float qk_scale = 0.044194173824159216f;  // 512^-0.5

  for (int b0 = 0; b0 < B; b0 += NB) {
    size_t xoff = (size_t)b0 * 262144;  // CIN*N
    size_t coff = (size_t)b0 * 59136;   // 77*768

    // GN1 + conv_in
    gn_stats_ext<<<NB * 32, 256, 0, stream>>>(x, xoff, flagp, stats1, 8, 256, 1024, 32);
    make_affine<<<(NB * 256 + 255) / 256, 256, 0, stream>>>(stats1, gn1_g, gn1_b, flagp, s1, t1, 256, 8, NB * 256);
    transpose_affine<<<dim3(16, NB), 256, 0, stream>>>(x, xoff, flagp, s1, t1, xT);
    mm<1, 0, 0, 0, 1, 0><<<dim3(4, 8, NB), 256, 0, stream>>>(
        w_in, 0, 256, 0, xT, 0, 256, 262144, U0, 0, 512, 524288,
        nullptr, 0, 0, 0.f, nullptr, b_in, flagp, 1.f, 1024, 256);

    // GN2 -> h1g
    gn_stats2<<<NB * 32, 256, 0, stream>>>(U0, stats2);
    make_affine<<<(NB * 512 + 255) / 256, 256, 0, stream>>>(stats2, sa_gn_g, sa_gn_b, flagp, s2, t2, 512, 16, NB * 512);
    affine_apply<<<NB * 512, 256, 0, stream>>>(U0, s2, t2, U1);

    // q, k, vT
    mm<1, 0, 0, 0, 0, 0><<<dim3(4, 8, NB), 256, 0, stream>>>(
        sa_wq, 0, 512, 0, U1, 0, 512, 524288, U2, 0, 512, 524288,
        nullptr, 0, 0, 0.f, nullptr, nullptr, flagp, 1.f, 1024, 512);
    mm<1, 0, 0, 0, 0, 0><<<dim3(4, 8, NB), 256, 0, stream>>>(
        sa_wk, 0, 512, 0, U1, 0, 512, 524288, U3, 0, 512, 524288,
        nullptr, 0, 0, 0.f, nullptr, nullptr, flagp, 1.f, 1024, 512);
    mm<0, 1, 0, 0, 0, 0><<<dim3(8, 4, NB), 256, 0, stream>>>(
        U1, 0, 512, 524288, sa_wv, 0, 512, 0, U4, 0, 1024, 524288,
        nullptr, 0, 0, 0.f, nullptr, nullptr, flagp, 1.f, 512, 512);

    // sim = scale*q@k^T ; softmax -> P ; o = P@v
    mm<0, 0, 1, 0, 0, 0><<<dim3(8, 8, NB), 256, 0, stream>>>(
        U3, 0, 512, 524288, U2, 0, 512, 524288, simb, 0, 1024, 1048576,
        nullptr, 0, 0, 0.f, nullptr, nullptr, flagp, qk_scale, 1024, 512);
    softmax1024<<<NB * 1024, 256, 0, stream>>>(simb, Pbuf);
    mm<0, 0, 0, 0, 0, 0><<<dim3(4, 8, NB), 256, 0, stream>>>(
        U4, 0, 1024, 524288, Pbuf, 0, 1024, 1048576, U1, 0, 512, 524288,
        nullptr, 0, 0, 0.f, nullptr, nullptr, flagp, 1.f, 1024, 1024);

    // h2 = wp@o + 2*h1
    mm<1, 0, 0, 0, 0, 1><<<dim3(4, 8, NB), 256, 0, stream>>>(
        sa_wp, 0, 512, 0, U1, 0, 512, 524288, U3, 0, 512, 524288,
        U0, 0, 524288, 2.f, nullptr, nullptr, flagp, 1.f, 1024, 512);

    // cross-attn
    mm<1, 0, 0, 0, 0, 0><<<dim3(4, 8, NB), 256, 0, stream>>>(
        ca_wq, 0, 512, 0, U3, 0, 512, 524288, U2, 0, 512, 524288,
        nullptr, 0, 0, 0.f, nullptr, nullptr, flagp, 1.f, 1024, 512);
    mm<1, 1, 0, 0, 0, 0><<<dim3(4, 1, NB), 256, 0, stream>>>(
        ca_wk, 0, 768, 0, ctx, coff, 768, 59136, k2, 0, 512, 39424,
        nullptr, 0, 0, 0.f, nullptr, nullptr, flagp, 1.f, 77, 768);
    mm<1, 1, 0, 0, 0, 0><<<dim3(4, 1, NB), 256, 0, stream>>>(
        ca_wv, 0, 768, 0, ctx, coff, 768, 59136, v2, 0, 512, 39424,
        nullptr, 0, 0, 0.f, nullptr, nullptr, flagp, 1.f, 77, 768);
    cross_sim_sm<<<dim3(32, 8, NB), 256, 0, stream>>>(U2, k2, P2);
    cross_av_k<<<dim3(32, 8, NB), 256, 0, stream>>>(P2, v2, U4);

    // h3 = wo@o2 + bo + h2
    mm<1, 0, 0, 0, 1, 1><<<dim3(4, 8, NB), 256, 0, stream>>>(
        ca_wo, 0, 512, 0, U4, 0, 512, 524288, U0, 0, 512, 524288,
        U3, 0, 524288, 1.f, nullptr, ca_bo, flagp, 1.f, 1024, 512);

    // y = w_out@h3 + b_out + x
    mm<0, 1, 2, 1, 0, 2><<<dim3(8, 2, NB), 256, 0, stream>>>(
        U0, 0, 512, 524288, w_out, 0, 512, 0, d_out, xoff, 1024, 262144,
        x, xoff, 262144, 1.f, b_out, nullptr, flagp, 1.f, 256, 512);
  }

  (void)in_sizes; (void)n_in; (void)out_size;
}

// Round 5
// 735.044 us; speedup vs baseline: 3.1325x; 1.5220x over previous
//
#include <hip/hip_runtime.h>
#include <math.h>

#define DEV __device__ __forceinline__

using f32x4 = __attribute__((ext_vector_type(4))) float;
using bf8   = __attribute__((ext_vector_type(8))) short;
using bf4   = __attribute__((ext_vector_type(4))) short;

// B=16, CIN=256, N=1024, INNER=512, CTX_N=77, CTX_D=768, HEADS=8, DH=64.
// Activations sequence-major [n][c] bf16 so every GEMM is C=A*B^T with K
// contiguous for both operands -> one generic MFMA kernel (16x16x32 bf16).

DEV short f2b(float x) {
  unsigned u = __builtin_bit_cast(unsigned, x);
  u += 0x7FFFu + ((u >> 16) & 1u);
  return (short)(u >> 16);
}
DEV float b2f(short s) {
  unsigned u = ((unsigned)(unsigned short)s) << 16;
  return __builtin_bit_cast(float, u);
}
DEV float ldin(const void* p, size_t i, int f) {
  return f ? reinterpret_cast<const float*>(p)[i]
           : b2f(reinterpret_cast<const short*>(p)[i]);
}

DEV float wave_max(float v) {
#pragma unroll
  for (int off = 32; off > 0; off >>= 1) v = fmaxf(v, __shfl_xor(v, off));
  return v;
}
DEV float wave_sum(float v) {
#pragma unroll
  for (int off = 32; off > 0; off >>= 1) v += __shfl_xor(v, off);
  return v;
}

// ---------------------------------------------------------------------------
// Dtype probe: fp32 data's low mantissa halves show exp-field 0x00/0xFF often;
// valid bf16 N(0,1) data never does. flag=1 -> fp32.
__global__ __launch_bounds__(256) void probe_dtype(const unsigned short* __restrict__ x,
                                                   int* __restrict__ flag) {
  __shared__ int cnt;
  if (threadIdx.x == 0) cnt = 0;
  __syncthreads();
  int c = 0;
  for (int i = threadIdx.x; i < 8192; i += 256) {
    int e = (x[i] >> 7) & 0xFF;
    if (e == 0xFF || e == 0x00) ++c;
  }
  atomicAdd(&cnt, c);
  __syncthreads();
  if (threadIdx.x == 0) flag[0] = (cnt >= 4) ? 1 : 0;
}

// ---------------------------------------------------------------------------
// GN1 stats on external x [b][C][N] channel-major (group = contiguous block).
__global__ __launch_bounds__(256) void gn_stats_ext(const void* __restrict__ x, size_t off,
                                                    const int* __restrict__ dflag,
                                                    float* __restrict__ stats,
                                                    int cpg, int C, int N, int G) {
  int f = dflag[0];
  int b = blockIdx.x / G;
  int g = blockIdx.x % G;
  size_t base = off + ((size_t)b * C + (size_t)g * cpg) * N;
  int count = cpg * N;
  float s = 0.f, ss = 0.f;
  for (int i = threadIdx.x; i < count; i += 256) {
    float v = ldin(x, base + i, f);
    s += v;
    ss += v * v;
  }
  s = wave_sum(s);
  ss = wave_sum(ss);
  __shared__ float r1[4], r2[4];
  int wid = threadIdx.x >> 6, lane = threadIdx.x & 63;
  if (lane == 0) { r1[wid] = s; r2[wid] = ss; }
  __syncthreads();
  if (threadIdx.x == 0) {
    s = r1[0] + r1[1] + r1[2] + r1[3];
    ss = r2[0] + r2[1] + r2[2] + r2[3];
    float mean = s / (float)count;
    float var = ss / (float)count - mean * mean;
    stats[blockIdx.x * 2 + 0] = mean;
    stats[blockIdx.x * 2 + 1] = rsqrtf(fmaxf(var, 0.f) + 1e-5f);
  }
}

// GN2 stats on internal bf16 h1 [b][1024][512] seq-major; group = 16 channels.
__global__ __launch_bounds__(256) void gn_stats2(const short* __restrict__ h1,
                                                 float* __restrict__ stats) {
  int b = blockIdx.x >> 5, g = blockIdx.x & 31;
  int cl = threadIdx.x & 15, nr = threadIdx.x >> 4;
  float s = 0.f, ss = 0.f;
  for (int n = nr; n < 1024; n += 16) {
    float v = b2f(h1[((size_t)b * 1024 + n) * 512 + g * 16 + cl]);
    s += v;
    ss += v * v;
  }
  s = wave_sum(s);
  ss = wave_sum(ss);
  __shared__ float r1[4], r2[4];
  int wid = threadIdx.x >> 6, lane = threadIdx.x & 63;
  if (lane == 0) { r1[wid] = s; r2[wid] = ss; }
  __syncthreads();
  if (threadIdx.x == 0) {
    s = r1[0] + r1[1] + r1[2] + r1[3];
    ss = r2[0] + r2[1] + r2[2] + r2[3];
    float mean = s / 16384.f;
    float var = ss / 16384.f - mean * mean;
    stats[blockIdx.x * 2 + 0] = mean;
    stats[blockIdx.x * 2 + 1] = rsqrtf(fmaxf(var, 0.f) + 1e-5f);
  }
}

// per-(b,c) affine coefficients
__global__ __launch_bounds__(256) void make_affine(const float* __restrict__ stats,
                                                   const void* __restrict__ gamma,
                                                   const void* __restrict__ beta,
                                                   const int* __restrict__ dflag,
                                                   float* __restrict__ sA, float* __restrict__ tA,
                                                   int C, int cpg, int total) {
  int f = dflag[0];
  int i = blockIdx.x * blockDim.x + threadIdx.x;
  if (i >= total) return;
  int b = i / C, c = i % C;
  int G = C / cpg;
  int g = c / cpg;
  float mean = stats[(b * G + g) * 2 + 0];
  float rstd = stats[(b * G + g) * 2 + 1];
  float gm = ldin(gamma, c, f);
  float bt = ldin(beta, c, f);
  sA[i] = rstd * gm;
  tA[i] = bt - mean * rstd * gm;
}

// ---------------------------------------------------------------------------
// x [b][256][1024] ext -> xT [b][1024][256] bf16 with GN1 affine.
__global__ __launch_bounds__(256) void transpose_affine(const void* __restrict__ x, size_t xoff,
                                                        const int* __restrict__ dflag,
                                                        const float* __restrict__ s1,
                                                        const float* __restrict__ t1,
                                                        short* __restrict__ xT) {
  int f = dflag[0];
  __shared__ short xs[64 * 264];
  int b = blockIdx.y, n0 = blockIdx.x * 64;
  int tid = threadIdx.x;
  for (int it = 0; it < 64; ++it) {
    int e = it * 256 + tid;
    int c = e >> 6, nl = e & 63;
    float v = ldin(x, xoff + ((size_t)b * 256 + c) * 1024 + n0 + nl, f);
    v = v * s1[b * 256 + c] + t1[b * 256 + c];
    xs[nl * 264 + c] = f2b(v);
  }
  __syncthreads();
  int nl = tid >> 2, cch = (tid & 3) * 64;
#pragma unroll
  for (int m = 0; m < 8; ++m)
    *(bf8*)&xT[((size_t)b * 1024 + n0 + nl) * 256 + cch + m * 8] =
        *(const bf8*)&xs[nl * 264 + cch + m * 8];
}

// h1 bf16 -> h1g bf16 with GN2 affine (per c).
__global__ __launch_bounds__(256) void affine_apply(const short* __restrict__ h1,
                                                    const float* __restrict__ s2,
                                                    const float* __restrict__ t2,
                                                    short* __restrict__ out) {
  size_t gid = (size_t)blockIdx.x * 256 + threadIdx.x;
  size_t base = gid * 4;
  int bl = (int)(base >> 19);
  int c = (int)(base & 511);
  bf4 v = *(const bf4*)&h1[base];
  bf4 o;
#pragma unroll
  for (int j = 0; j < 4; ++j)
    o[j] = f2b(b2f(v[j]) * s2[bl * 512 + c + j] + t2[bl * 512 + c + j]);
  *(bf4*)&out[base] = o;
}

// ---------------------------------------------------------------------------
// Generic MFMA GEMM: OUT[z][p][q] = scale * sum_k Bm[p][k]*Am[q][k] (+biases/res)
// q is the contiguous output dim. A-slot gets Am (q rows), B-slot gets Bm (p rows).
// D layout: col(lane&15)=p-local, row(quad*4+reg)=q-local -> 4-consecutive-q stores.
// A_EXT/B_EXT: operand dtype external(flagged) vs internal bf16.
// OUT_T: 0 bf16, 1 fp32, 2 external. RES_T: 0 none, 1 bf16, 2 external.
template <int A_EXT, int B_EXT, int OUT_T, int BIAS_P_, int BIAS_Q_, int RES_T>
__global__ __launch_bounds__(256) void mm(
    const void* __restrict__ Am, size_t aoff, int lda, size_t zsa,
    const void* __restrict__ Bm, size_t boff, int ldb, size_t zsb,
    void* __restrict__ Out, size_t ooff, int ldc, size_t zsc,
    const void* __restrict__ Res, size_t roff, size_t zsr, float res_scale,
    const void* __restrict__ biasP, const void* __restrict__ biasQ,
    const int* __restrict__ dflag, float scale, int P, int K) {
  const int f = dflag[0];
  __shared__ short lA[128 * 40];
  __shared__ short lB[128 * 40];
  const int tid = threadIdx.x;
  const int z = blockIdx.z;
  const int q0 = blockIdx.x * 128, p0 = blockIdx.y * 128;
  const int l = tid & 63;
  const int w = tid >> 6;
  const int wq = (w & 1) * 64, wp = (w >> 1) * 64;
  const int lm = l & 15, quad = l >> 4;
  const int sr = tid >> 1;
  const int sc = (tid & 1) << 4;
  const size_t abase = aoff + (size_t)z * zsa + (size_t)(q0 + sr) * lda + sc;
  const size_t bbase = boff + (size_t)z * zsb + (size_t)(p0 + sr) * ldb + sc;
  const bool bvalid = (p0 + sr) < P;

  f32x4 acc[4][4];
#pragma unroll
  for (int i = 0; i < 4; ++i)
#pragma unroll
    for (int j = 0; j < 4; ++j) acc[i][j] = (f32x4){0.f, 0.f, 0.f, 0.f};

  for (int kk = 0; kk < K; kk += 32) {
    __syncthreads();
    short va[16], vb[16];
    {
      size_t g = abase + kk;
      if (A_EXT && f) {
        const float* p = reinterpret_cast<const float*>(Am);
#pragma unroll
        for (int i = 0; i < 16; i += 4) {
          float4 t4 = *(const float4*)&p[g + i];
          va[i] = f2b(t4.x); va[i + 1] = f2b(t4.y);
          va[i + 2] = f2b(t4.z); va[i + 3] = f2b(t4.w);
        }
      } else {
        const short* p = reinterpret_cast<const short*>(Am);
        *(bf8*)&va[0] = *(const bf8*)&p[g];
        *(bf8*)&va[8] = *(const bf8*)&p[g + 8];
      }
    }
    if (bvalid) {
      size_t g = bbase + kk;
      if (B_EXT && f) {
        const float* p = reinterpret_cast<const float*>(Bm);
#pragma unroll
        for (int i = 0; i < 16; i += 4) {
          float4 t4 = *(const float4*)&p[g + i];
          vb[i] = f2b(t4.x); vb[i + 1] = f2b(t4.y);
          vb[i + 2] = f2b(t4.z); vb[i + 3] = f2b(t4.w);
        }
      } else {
        const short* p = reinterpret_cast<const short*>(Bm);
        *(bf8*)&vb[0] = *(const bf8*)&p[g];
        *(bf8*)&vb[8] = *(const bf8*)&p[g + 8];
      }
    } else {
#pragma unroll
      for (int i = 0; i < 16; ++i) vb[i] = 0;
    }
    *(bf8*)&lA[sr * 40 + sc] = *(bf8*)&va[0];
    *(bf8*)&lA[sr * 40 + sc + 8] = *(bf8*)&va[8];
    *(bf8*)&lB[sr * 40 + sc] = *(bf8*)&vb[0];
    *(bf8*)&lB[sr * 40 + sc + 8] = *(bf8*)&vb[8];
    __syncthreads();

    bf8 af[4], bfr[4];
#pragma unroll
    for (int i = 0; i < 4; ++i)
      af[i] = *(const bf8*)&lA[(wq + i * 16 + lm) * 40 + quad * 8];
#pragma unroll
    for (int i = 0; i < 4; ++i)
      bfr[i] = *(const bf8*)&lB[(wp + i * 16 + lm) * 40 + quad * 8];
#pragma unroll
    for (int qi = 0; qi < 4; ++qi)
#pragma unroll
      for (int pi = 0; pi < 4; ++pi)
        acc[qi][pi] = __builtin_amdgcn_mfma_f32_16x16x32_bf16(af[qi], bfr[pi], acc[qi][pi], 0, 0, 0);
  }

  const size_t obase = ooff + (size_t)z * zsc;
#pragma unroll
  for (int pi = 0; pi < 4; ++pi) {
    int p = p0 + wp + pi * 16 + lm;
    if (p >= P) continue;
    float bp = BIAS_P_ ? ldin(biasP, p, f) : 0.f;
#pragma unroll
    for (int qi = 0; qi < 4; ++qi) {
      int q = q0 + wq + qi * 16 + quad * 4;
      f32x4 d = acc[qi][pi];
      float v[4];
#pragma unroll
      for (int r = 0; r < 4; ++r) {
        v[r] = d[r] * scale + bp;
        if (BIAS_Q_) v[r] += ldin(biasQ, q + r, f);
      }
      if (RES_T == 1) {
        bf4 rv = *(const bf4*)&reinterpret_cast<const short*>(Res)[roff + (size_t)z * zsr + (size_t)p * ldc + q];
#pragma unroll
        for (int r = 0; r < 4; ++r) v[r] += res_scale * b2f(rv[r]);
      } else if (RES_T == 2) {
        size_t ri = roff + (size_t)z * zsr + (size_t)p * ldc + q;
        if (f) {
          float4 rf = *(const float4*)&reinterpret_cast<const float*>(Res)[ri];
          v[0] += res_scale * rf.x; v[1] += res_scale * rf.y;
          v[2] += res_scale * rf.z; v[3] += res_scale * rf.w;
        } else {
          bf4 rv = *(const bf4*)&reinterpret_cast<const short*>(Res)[ri];
#pragma unroll
          for (int r = 0; r < 4; ++r) v[r] += res_scale * b2f(rv[r]);
        }
      }
      size_t idx = obase + (size_t)p * ldc + q;
      if (OUT_T == 0) {
        bf4 o;
#pragma unroll
        for (int r = 0; r < 4; ++r) o[r] = f2b(v[r]);
        *(bf4*)&reinterpret_cast<short*>(Out)[idx] = o;
      } else if (OUT_T == 1) {
        f32x4 o = {v[0], v[1], v[2], v[3]};
        *(f32x4*)&reinterpret_cast<float*>(Out)[idx] = o;
      } else {
        if (f) {
          f32x4 o = {v[0], v[1], v[2], v[3]};
          *(f32x4*)&reinterpret_cast<float*>(Out)[idx] = o;
        } else {
          bf4 o;
#pragma unroll
          for (int r = 0; r < 4; ++r) o[r] = f2b(v[r]);
          *(bf4*)&reinterpret_cast<short*>(Out)[idx] = o;
        }
      }
    }
  }
}

// ---------------------------------------------------------------------------
// Softmax over rows of 1024: fp32 sim in, bf16 P out.
__global__ __launch_bounds__(256) void softmax1024(const float* __restrict__ sim,
                                                   short* __restrict__ P) {
  const float* row = sim + (size_t)blockIdx.x * 1024;
  int t = threadIdx.x;
  float4 v = ((const float4*)row)[t];
  float m = fmaxf(fmaxf(v.x, v.y), fmaxf(v.z, v.w));
  m = wave_max(m);
  __shared__ float red[4], red2[4];
  int wid = t >> 6, lane = t & 63;
  if (lane == 0) red[wid] = m;
  __syncthreads();
  m = fmaxf(fmaxf(red[0], red[1]), fmaxf(red[2], red[3]));
  v.x = __expf(v.x - m); v.y = __expf(v.y - m);
  v.z = __expf(v.z - m); v.w = __expf(v.w - m);
  float s = v.x + v.y + v.z + v.w;
  s = wave_sum(s);
  if (lane == 0) red2[wid] = s;
  __syncthreads();
  s = red2[0] + red2[1] + red2[2] + red2[3];
  float inv = 1.f / s;
  bf4 o;
  o[0] = f2b(v.x * inv); o[1] = f2b(v.y * inv);
  o[2] = f2b(v.z * inv); o[3] = f2b(v.w * inv);
  ((bf4*)(P + (size_t)blockIdx.x * 1024))[t] = o;
}

// ---------------------------------------------------------------------------
// Fused cross-attention (scores + softmax + AV) per (b, h, 32 q-rows).
// Spill-free: 10 j-accumulators, K chunked into register blocks of 8.
__global__ __launch_bounds__(256) void cross_attn(const short* __restrict__ q2,
                                                  const short* __restrict__ k2,
                                                  const short* __restrict__ v2,
                                                  short* __restrict__ o2) {
  __shared__ float ks[80][65];
  __shared__ float vs[77][65];
  __shared__ float qs[32][65];
  __shared__ float sc[32][81];
  const int b = blockIdx.z, h = blockIdx.y, i0 = blockIdx.x * 32;
  const int tid = threadIdx.x;
  for (int idx = tid; idx < 80 * 64; idx += 256) {
    int j = idx >> 6, d = idx & 63;
    ks[j][d] = (j < 77) ? b2f(k2[(size_t)b * 39424 + j * 512 + h * 64 + d]) : 0.f;
  }
  for (int idx = tid; idx < 77 * 64; idx += 256) {
    int j = idx >> 6, d = idx & 63;
    vs[j][d] = b2f(v2[(size_t)b * 39424 + j * 512 + h * 64 + d]);
  }
  for (int idx = tid; idx < 32 * 64; idx += 256) {
    int il = idx >> 6, d = idx & 63;
    qs[il][d] = b2f(q2[((size_t)b * 1024 + i0 + il) * 512 + h * 64 + d]);
  }
  __syncthreads();
  {
    const int il = tid >> 3, jg = tid & 7;
    float acc[10];
#pragma unroll
    for (int jj = 0; jj < 10; ++jj) acc[jj] = 0.f;
    for (int d0 = 0; d0 < 64; d0 += 8) {
      float qv[8];
#pragma unroll
      for (int dd = 0; dd < 8; ++dd) qv[dd] = qs[il][d0 + dd];
#pragma unroll
      for (int jj = 0; jj < 10; ++jj) {
        int j = jg + jj * 8;
#pragma unroll
        for (int dd = 0; dd < 8; ++dd) acc[jj] = fmaf(qv[dd], ks[j][d0 + dd], acc[jj]);
      }
    }
    float mx = -1e30f;
#pragma unroll
    for (int jj = 0; jj < 10; ++jj) {
      int j = jg + jj * 8;
      acc[jj] = (j < 77) ? acc[jj] * 0.125f : -1e30f;
      mx = fmaxf(mx, acc[jj]);
    }
    mx = fmaxf(mx, __shfl_xor(mx, 1));
    mx = fmaxf(mx, __shfl_xor(mx, 2));
    mx = fmaxf(mx, __shfl_xor(mx, 4));
    float s = 0.f;
#pragma unroll
    for (int jj = 0; jj < 10; ++jj) {
      acc[jj] = __expf(acc[jj] - mx);
      s += acc[jj];
    }
    s += __shfl_xor(s, 1);
    s += __shfl_xor(s, 2);
    s += __shfl_xor(s, 4);
    float inv = 1.f / s;
#pragma unroll
    for (int jj = 0; jj < 10; ++jj) sc[il][jg + jj * 8] = acc[jj] * inv;
  }
  __syncthreads();
  {
    const int il = tid >> 3, cg = tid & 7;
    float a[8] = {0.f, 0.f, 0.f, 0.f, 0.f, 0.f, 0.f, 0.f};
    for (int j = 0; j < 77; ++j) {
      float p = sc[il][j];
#pragma unroll
      for (int m = 0; m < 8; ++m) a[m] = fmaf(p, vs[j][cg + 8 * m], a[m]);
    }
#pragma unroll
    for (int m = 0; m < 8; ++m)
      o2[((size_t)b * 1024 + i0 + il) * 512 + h * 64 + cg + 8 * m] = f2b(a[m]);
  }
}

// ---------------------------------------------------------------------------
extern "C" void kernel_launch(void* const* d_in, const int* in_sizes, int n_in,
                              void* d_out, int out_size, void* d_ws, size_t ws_size,
                              hipStream_t stream) {
  const void* x       = d_in[0];
  const void* ctx     = d_in[1];
  const void* gn1_g   = d_in[2];
  const void* gn1_b   = d_in[3];
  const void* w_in    = d_in[4];
  const void* b_in    = d_in[5];
  const void* sa_wk   = d_in[6];
  const void* sa_wq   = d_in[7];
  const void* sa_wv   = d_in[8];
  const void* sa_wp   = d_in[9];
  const void* sa_gn_g = d_in[10];
  const void* sa_gn_b = d_in[11];
  const void* ca_wq   = d_in[12];
  const void* ca_wk   = d_in[13];
  const void* ca_wv   = d_in[14];
  const void* ca_wo   = d_in[15];
  const void* ca_bo   = d_in[16];
  const void* w_out   = d_in[17];
  const void* b_out   = d_in[18];

  const int B = 16;
  // footprint = 128KB + NB * 11 MB
  int NB = 16;
  while (NB > 1 && 131072ull + (size_t)NB * 11534336ull > ws_size) NB >>= 1;

  char* base = reinterpret_cast<char*>(d_ws);
  int* flagp = reinterpret_cast<int*>(base);
  float* smf = reinterpret_cast<float*>(base + 1024);
  float* stats1 = smf;
  float* stats2 = smf + 1024;
  float* s1 = smf + 2048;
  float* t1 = smf + 6144;
  float* s2 = smf + 10240;
  float* t2 = smf + 18432;
  char* big = base + 131072;
  const size_t MB = 1048576;
  short* U0 = (short*)(big + 0 * (size_t)NB * MB);  // h1 -> h3
  short* U1 = (short*)(big + 1 * (size_t)NB * MB);  // h1g -> o_attn
  short* U2 = (short*)(big + 2 * (size_t)NB * MB);  // q -> q2
  short* U3 = (short*)(big + 3 * (size_t)NB * MB);  // k -> h2
  short* U4 = (short*)(big + 4 * (size_t)NB * MB);  // vT -> o2
  char* Sreg = big + 5 * (size_t)NB * MB;           // 6 MB/b region
  float* simb = (float*)Sreg;                          // [NB,1024,1024] fp32
  short* Pbuf = (short*)(Sreg + (size_t)NB * 4 * MB);  // [NB,1024,1024] bf16
  short* xT = (short*)Sreg;                            // [NB,1024,256] bf16 (pre-sim)
  short* k2 = (short*)Sreg;                            // [NB,77,512] bf16 (post-sim)
  short* v2 = (short*)(Sreg + (size_t)NB * 78848);

  probe_dtype<<<1, 256, 0, stream>>>((const unsigned short*)x, flagp);

  const float qk_scale = 0.044194173824159216f;  // 512^-0.5

  for (int b0 = 0; b0 < B; b0 += NB) {
    size_t xoff = (size_t)b0 * 262144;  // CIN*N
    size_t coff = (size_t)b0 * 59136;   // 77*768

    // GN1 + conv_in
    gn_stats_ext<<<NB * 32, 256, 0, stream>>>(x, xoff, flagp, stats1, 8, 256, 1024, 32);
    make_affine<<<(NB * 256 + 255) / 256, 256, 0, stream>>>(stats1, gn1_g, gn1_b, flagp, s1, t1, 256, 8, NB * 256);
    transpose_affine<<<dim3(16, NB), 256, 0, stream>>>(x, xoff, flagp, s1, t1, xT);
    mm<1, 0, 0, 0, 1, 0><<<dim3(4, 8, NB), 256, 0, stream>>>(
        w_in, 0, 256, 0, xT, 0, 256, 262144, U0, 0, 512, 524288,
        nullptr, 0, 0, 0.f, nullptr, b_in, flagp, 1.f, 1024, 256);

    // GN2 -> h1g
    gn_stats2<<<NB * 32, 256, 0, stream>>>(U0, stats2);
    make_affine<<<(NB * 512 + 255) / 256, 256, 0, stream>>>(stats2, sa_gn_g, sa_gn_b, flagp, s2, t2, 512, 16, NB * 512);
    affine_apply<<<NB * 512, 256, 0, stream>>>(U0, s2, t2, U1);

    // q, k, vT
    mm<1, 0, 0, 0, 0, 0><<<dim3(4, 8, NB), 256, 0, stream>>>(
        sa_wq, 0, 512, 0, U1, 0, 512, 524288, U2, 0, 512, 524288,
        nullptr, 0, 0, 0.f, nullptr, nullptr, flagp, 1.f, 1024, 512);
    mm<1, 0, 0, 0, 0, 0><<<dim3(4, 8, NB), 256, 0, stream>>>(
        sa_wk, 0, 512, 0, U1, 0, 512, 524288, U3, 0, 512, 524288,
        nullptr, 0, 0, 0.f, nullptr, nullptr, flagp, 1.f, 1024, 512);
    mm<0, 1, 0, 0, 0, 0><<<dim3(8, 4, NB), 256, 0, stream>>>(
        U1, 0, 512, 524288, sa_wv, 0, 512, 0, U4, 0, 1024, 524288,
        nullptr, 0, 0, 0.f, nullptr, nullptr, flagp, 1.f, 512, 512);

    // sim = scale*q@k^T ; softmax -> P ; o = P@v
    mm<0, 0, 1, 0, 0, 0><<<dim3(8, 8, NB), 256, 0, stream>>>(
        U3, 0, 512, 524288, U2, 0, 512, 524288, simb, 0, 1024, 1048576,
        nullptr, 0, 0, 0.f, nullptr, nullptr, flagp, qk_scale, 1024, 512);
    softmax1024<<<NB * 1024, 256, 0, stream>>>(simb, Pbuf);
    mm<0, 0, 0, 0, 0, 0><<<dim3(4, 8, NB), 256, 0, stream>>>(
        U4, 0, 1024, 524288, Pbuf, 0, 1024, 1048576, U1, 0, 512, 524288,
        nullptr, 0, 0, 0.f, nullptr, nullptr, flagp, 1.f, 1024, 1024);

    // h2 = wp@o + 2*h1
    mm<1, 0, 0, 0, 0, 1><<<dim3(4, 8, NB), 256, 0, stream>>>(
        sa_wp, 0, 512, 0, U1, 0, 512, 524288, U3, 0, 512, 524288,
        U0, 0, 524288, 2.f, nullptr, nullptr, flagp, 1.f, 1024, 512);

    // cross-attn
    mm<1, 0, 0, 0, 0, 0><<<dim3(4, 8, NB), 256, 0, stream>>>(
        ca_wq, 0, 512, 0, U3, 0, 512, 524288, U2, 0, 512, 524288,
        nullptr, 0, 0, 0.f, nullptr, nullptr, flagp, 1.f, 1024, 512);
    mm<1, 1, 0, 0, 0, 0><<<dim3(4, 1, NB), 256, 0, stream>>>(
        ca_wk, 0, 768, 0, ctx, coff, 768, 59136, k2, 0, 512, 39424,
        nullptr, 0, 0, 0.f, nullptr, nullptr, flagp, 1.f, 77, 768);
    mm<1, 1, 0, 0, 0, 0><<<dim3(4, 1, NB), 256, 0, stream>>>(
        ca_wv, 0, 768, 0, ctx, coff, 768, 59136, v2, 0, 512, 39424,
        nullptr, 0, 0, 0.f, nullptr, nullptr, flagp, 1.f, 77, 768);
    cross_attn<<<dim3(32, 8, NB), 256, 0, stream>>>(U2, k2, v2, U4);

    // h3 = wo@o2 + bo + h2
    mm<1, 0, 0, 0, 1, 1><<<dim3(4, 8, NB), 256, 0, stream>>>(
        ca_wo, 0, 512, 0, U4, 0, 512, 524288, U0, 0, 512, 524288,
        U3, 0, 524288, 1.f, nullptr, ca_bo, flagp, 1.f, 1024, 512);

    // y = w_out@h3 + b_out + x
    mm<0, 1, 2, 1, 0, 2><<<dim3(8, 2, NB), 256, 0, stream>>>(
        U0, 0, 512, 524288, w_out, 0, 512, 0, d_out, xoff, 1024, 262144,
        x, xoff, 262144, 1.f, b_out, nullptr, flagp, 1.f, 256, 512);
  }

  (void)in_sizes; (void)n_in; (void)out_size;
}

// Round 6
// 620.305 us; speedup vs baseline: 3.7119x; 1.1850x over previous
//
#include <hip/hip_runtime.h>
#include <math.h>

#define DEV __device__ __forceinline__

using f32x4 = __attribute__((ext_vector_type(4))) float;
using bf8   = __attribute__((ext_vector_type(8))) short;
using bf4   = __attribute__((ext_vector_type(4))) short;

// B=16, CIN=256, N=1024, INNER=512, CTX_N=77, CTX_D=768, HEADS=8, DH=64.
// Activations sequence-major [n][c] bf16 so every GEMM is C=A*B^T with K
// contiguous for both operands -> one generic MFMA kernel (16x16x32 bf16).

DEV short f2b(float x) {
  unsigned u = __builtin_bit_cast(unsigned, x);
  u += 0x7FFFu + ((u >> 16) & 1u);
  return (short)(u >> 16);
}
DEV float b2f(short s) {
  unsigned u = ((unsigned)(unsigned short)s) << 16;
  return __builtin_bit_cast(float, u);
}
DEV float ldin(const void* p, size_t i, int f) {
  return f ? reinterpret_cast<const float*>(p)[i]
           : b2f(reinterpret_cast<const short*>(p)[i]);
}

DEV float wave_max(float v) {
#pragma unroll
  for (int off = 32; off > 0; off >>= 1) v = fmaxf(v, __shfl_xor(v, off));
  return v;
}
DEV float wave_sum(float v) {
#pragma unroll
  for (int off = 32; off > 0; off >>= 1) v += __shfl_xor(v, off);
  return v;
}

// ---------------------------------------------------------------------------
// Dtype probe: fp32 data's low mantissa halves show exp-field 0x00/0xFF often;
// valid bf16 N(0,1) data never does. flag=1 -> fp32.
__global__ __launch_bounds__(256) void probe_dtype(const unsigned short* __restrict__ x,
                                                   int* __restrict__ flag) {
  __shared__ int cnt;
  if (threadIdx.x == 0) cnt = 0;
  __syncthreads();
  int c = 0;
  for (int i = threadIdx.x; i < 8192; i += 256) {
    int e = (x[i] >> 7) & 0xFF;
    if (e == 0xFF || e == 0x00) ++c;
  }
  atomicAdd(&cnt, c);
  __syncthreads();
  if (threadIdx.x == 0) flag[0] = (cnt >= 4) ? 1 : 0;
}

// ---------------------------------------------------------------------------
// GN1 stats on external x [b][C][N] channel-major (group = contiguous block).
__global__ __launch_bounds__(256) void gn_stats_ext(const void* __restrict__ x, size_t off,
                                                    const int* __restrict__ dflag,
                                                    float* __restrict__ stats,
                                                    int cpg, int C, int N, int G) {
  int f = dflag[0];
  int b = blockIdx.x / G;
  int g = blockIdx.x % G;
  size_t base = off + ((size_t)b * C + (size_t)g * cpg) * N;
  int count = cpg * N;
  float s = 0.f, ss = 0.f;
  for (int i = threadIdx.x; i < count; i += 256) {
    float v = ldin(x, base + i, f);
    s += v;
    ss += v * v;
  }
  s = wave_sum(s);
  ss = wave_sum(ss);
  __shared__ float r1[4], r2[4];
  int wid = threadIdx.x >> 6, lane = threadIdx.x & 63;
  if (lane == 0) { r1[wid] = s; r2[wid] = ss; }
  __syncthreads();
  if (threadIdx.x == 0) {
    s = r1[0] + r1[1] + r1[2] + r1[3];
    ss = r2[0] + r2[1] + r2[2] + r2[3];
    float mean = s / (float)count;
    float var = ss / (float)count - mean * mean;
    stats[blockIdx.x * 2 + 0] = mean;
    stats[blockIdx.x * 2 + 1] = rsqrtf(fmaxf(var, 0.f) + 1e-5f);
  }
}

// GN2 stats on internal bf16 h1 [b][1024][512] seq-major; group = 16 channels.
__global__ __launch_bounds__(256) void gn_stats2(const short* __restrict__ h1,
                                                 float* __restrict__ stats) {
  int b = blockIdx.x >> 5, g = blockIdx.x & 31;
  int cl = threadIdx.x & 15, nr = threadIdx.x >> 4;
  float s = 0.f, ss = 0.f;
  for (int n = nr; n < 1024; n += 16) {
    float v = b2f(h1[((size_t)b * 1024 + n) * 512 + g * 16 + cl]);
    s += v;
    ss += v * v;
  }
  s = wave_sum(s);
  ss = wave_sum(ss);
  __shared__ float r1[4], r2[4];
  int wid = threadIdx.x >> 6, lane = threadIdx.x & 63;
  if (lane == 0) { r1[wid] = s; r2[wid] = ss; }
  __syncthreads();
  if (threadIdx.x == 0) {
    s = r1[0] + r1[1] + r1[2] + r1[3];
    ss = r2[0] + r2[1] + r2[2] + r2[3];
    float mean = s / 16384.f;
    float var = ss / 16384.f - mean * mean;
    stats[blockIdx.x * 2 + 0] = mean;
    stats[blockIdx.x * 2 + 1] = rsqrtf(fmaxf(var, 0.f) + 1e-5f);
  }
}

// per-(b,c) affine coefficients
__global__ __launch_bounds__(256) void make_affine(const float* __restrict__ stats,
                                                   const void* __restrict__ gamma,
                                                   const void* __restrict__ beta,
                                                   const int* __restrict__ dflag,
                                                   float* __restrict__ sA, float* __restrict__ tA,
                                                   int C, int cpg, int total) {
  int f = dflag[0];
  int i = blockIdx.x * blockDim.x + threadIdx.x;
  if (i >= total) return;
  int b = i / C, c = i % C;
  int G = C / cpg;
  int g = c / cpg;
  float mean = stats[(b * G + g) * 2 + 0];
  float rstd = stats[(b * G + g) * 2 + 1];
  float gm = ldin(gamma, c, f);
  float bt = ldin(beta, c, f);
  sA[i] = rstd * gm;
  tA[i] = bt - mean * rstd * gm;
}

// ---------------------------------------------------------------------------
// x [b][256][1024] ext -> xT [b][1024][256] bf16 with GN1 affine.
__global__ __launch_bounds__(256) void transpose_affine(const void* __restrict__ x, size_t xoff,
                                                        const int* __restrict__ dflag,
                                                        const float* __restrict__ s1,
                                                        const float* __restrict__ t1,
                                                        short* __restrict__ xT) {
  int f = dflag[0];
  __shared__ short xs[64 * 264];
  int b = blockIdx.y, n0 = blockIdx.x * 64;
  int tid = threadIdx.x;
  for (int it = 0; it < 64; ++it) {
    int e = it * 256 + tid;
    int c = e >> 6, nl = e & 63;
    float v = ldin(x, xoff + ((size_t)b * 256 + c) * 1024 + n0 + nl, f);
    v = v * s1[b * 256 + c] + t1[b * 256 + c];
    xs[nl * 264 + c] = f2b(v);
  }
  __syncthreads();
  int nl = tid >> 2, cch = (tid & 3) * 64;
#pragma unroll
  for (int m = 0; m < 8; ++m)
    *(bf8*)&xT[((size_t)b * 1024 + n0 + nl) * 256 + cch + m * 8] =
        *(const bf8*)&xs[nl * 264 + cch + m * 8];
}

// h1 bf16 -> h1g bf16 with GN2 affine (per c).
__global__ __launch_bounds__(256) void affine_apply(const short* __restrict__ h1,
                                                    const float* __restrict__ s2,
                                                    const float* __restrict__ t2,
                                                    short* __restrict__ out) {
  size_t gid = (size_t)blockIdx.x * 256 + threadIdx.x;
  size_t base = gid * 4;
  int bl = (int)(base >> 19);
  int c = (int)(base & 511);
  bf4 v = *(const bf4*)&h1[base];
  bf4 o;
#pragma unroll
  for (int j = 0; j < 4; ++j)
    o[j] = f2b(b2f(v[j]) * s2[bl * 512 + c + j] + t2[bl * 512 + c + j]);
  *(bf4*)&out[base] = o;
}

// ---------------------------------------------------------------------------
// Generic MFMA GEMM: OUT[z][p][q] = scale * sum_k Bm[p][k]*Am[q][k] (+biases/res)
// q is the contiguous output dim. A-slot gets Am (q rows), B-slot gets Bm (p rows).
// D layout: col(lane&15)=p-local, row(quad*4+reg)=q-local -> 4-consecutive-q stores.
// A_EXT/B_EXT: operand dtype external(flagged) vs internal bf16.
// OUT_T: 0 bf16, 1 fp32, 2 external. RES_T: 0 none, 1 bf16, 2 external.
template <int A_EXT, int B_EXT, int OUT_T, int BIAS_P_, int BIAS_Q_, int RES_T>
__global__ __launch_bounds__(256) void mm(
    const void* __restrict__ Am, size_t aoff, int lda, size_t zsa,
    const void* __restrict__ Bm, size_t boff, int ldb, size_t zsb,
    void* __restrict__ Out, size_t ooff, int ldc, size_t zsc,
    const void* __restrict__ Res, size_t roff, size_t zsr, float res_scale,
    const void* __restrict__ biasP, const void* __restrict__ biasQ,
    const int* __restrict__ dflag, float scale, int P, int K) {
  const int f = dflag[0];
  __shared__ short lA[128 * 40];
  __shared__ short lB[128 * 40];
  const int tid = threadIdx.x;
  const int z = blockIdx.z;
  const int q0 = blockIdx.x * 128, p0 = blockIdx.y * 128;
  const int l = tid & 63;
  const int w = tid >> 6;
  const int wq = (w & 1) * 64, wp = (w >> 1) * 64;
  const int lm = l & 15, quad = l >> 4;
  const int sr = tid >> 1;
  const int sc = (tid & 1) << 4;
  const size_t abase = aoff + (size_t)z * zsa + (size_t)(q0 + sr) * lda + sc;
  const size_t bbase = boff + (size_t)z * zsb + (size_t)(p0 + sr) * ldb + sc;
  const bool bvalid = (p0 + sr) < P;

  f32x4 acc[4][4];
#pragma unroll
  for (int i = 0; i < 4; ++i)
#pragma unroll
    for (int j = 0; j < 4; ++j) acc[i][j] = (f32x4){0.f, 0.f, 0.f, 0.f};

  for (int kk = 0; kk < K; kk += 32) {
    __syncthreads();
    short va[16], vb[16];
    {
      size_t g = abase + kk;
      if (A_EXT && f) {
        const float* p = reinterpret_cast<const float*>(Am);
#pragma unroll
        for (int i = 0; i < 16; i += 4) {
          float4 t4 = *(const float4*)&p[g + i];
          va[i] = f2b(t4.x); va[i + 1] = f2b(t4.y);
          va[i + 2] = f2b(t4.z); va[i + 3] = f2b(t4.w);
        }
      } else {
        const short* p = reinterpret_cast<const short*>(Am);
        *(bf8*)&va[0] = *(const bf8*)&p[g];
        *(bf8*)&va[8] = *(const bf8*)&p[g + 8];
      }
    }
    if (bvalid) {
      size_t g = bbase + kk;
      if (B_EXT && f) {
        const float* p = reinterpret_cast<const float*>(Bm);
#pragma unroll
        for (int i = 0; i < 16; i += 4) {
          float4 t4 = *(const float4*)&p[g + i];
          vb[i] = f2b(t4.x); vb[i + 1] = f2b(t4.y);
          vb[i + 2] = f2b(t4.z); vb[i + 3] = f2b(t4.w);
        }
      } else {
        const short* p = reinterpret_cast<const short*>(Bm);
        *(bf8*)&vb[0] = *(const bf8*)&p[g];
        *(bf8*)&vb[8] = *(const bf8*)&p[g + 8];
      }
    } else {
#pragma unroll
      for (int i = 0; i < 16; ++i) vb[i] = 0;
    }
    *(bf8*)&lA[sr * 40 + sc] = *(bf8*)&va[0];
    *(bf8*)&lA[sr * 40 + sc + 8] = *(bf8*)&va[8];
    *(bf8*)&lB[sr * 40 + sc] = *(bf8*)&vb[0];
    *(bf8*)&lB[sr * 40 + sc + 8] = *(bf8*)&vb[8];
    __syncthreads();

    bf8 af[4], bfr[4];
#pragma unroll
    for (int i = 0; i < 4; ++i)
      af[i] = *(const bf8*)&lA[(wq + i * 16 + lm) * 40 + quad * 8];
#pragma unroll
    for (int i = 0; i < 4; ++i)
      bfr[i] = *(const bf8*)&lB[(wp + i * 16 + lm) * 40 + quad * 8];
#pragma unroll
    for (int qi = 0; qi < 4; ++qi)
#pragma unroll
      for (int pi = 0; pi < 4; ++pi)
        acc[qi][pi] = __builtin_amdgcn_mfma_f32_16x16x32_bf16(af[qi], bfr[pi], acc[qi][pi], 0, 0, 0);
  }

  const size_t obase = ooff + (size_t)z * zsc;
#pragma unroll
  for (int pi = 0; pi < 4; ++pi) {
    int p = p0 + wp + pi * 16 + lm;
    if (p >= P) continue;
    float bp = BIAS_P_ ? ldin(biasP, p, f) : 0.f;
#pragma unroll
    for (int qi = 0; qi < 4; ++qi) {
      int q = q0 + wq + qi * 16 + quad * 4;
      f32x4 d = acc[qi][pi];
      float v[4];
#pragma unroll
      for (int r = 0; r < 4; ++r) {
        v[r] = d[r] * scale + bp;
        if (BIAS_Q_) v[r] += ldin(biasQ, q + r, f);
      }
      if (RES_T == 1) {
        bf4 rv = *(const bf4*)&reinterpret_cast<const short*>(Res)[roff + (size_t)z * zsr + (size_t)p * ldc + q];
#pragma unroll
        for (int r = 0; r < 4; ++r) v[r] += res_scale * b2f(rv[r]);
      } else if (RES_T == 2) {
        size_t ri = roff + (size_t)z * zsr + (size_t)p * ldc + q;
        if (f) {
          float4 rf = *(const float4*)&reinterpret_cast<const float*>(Res)[ri];
          v[0] += res_scale * rf.x; v[1] += res_scale * rf.y;
          v[2] += res_scale * rf.z; v[3] += res_scale * rf.w;
        } else {
          bf4 rv = *(const bf4*)&reinterpret_cast<const short*>(Res)[ri];
#pragma unroll
          for (int r = 0; r < 4; ++r) v[r] += res_scale * b2f(rv[r]);
        }
      }
      size_t idx = obase + (size_t)p * ldc + q;
      if (OUT_T == 0) {
        bf4 o;
#pragma unroll
        for (int r = 0; r < 4; ++r) o[r] = f2b(v[r]);
        *(bf4*)&reinterpret_cast<short*>(Out)[idx] = o;
      } else if (OUT_T == 1) {
        f32x4 o = {v[0], v[1], v[2], v[3]};
        *(f32x4*)&reinterpret_cast<float*>(Out)[idx] = o;
      } else {
        if (f) {
          f32x4 o = {v[0], v[1], v[2], v[3]};
          *(f32x4*)&reinterpret_cast<float*>(Out)[idx] = o;
        } else {
          bf4 o;
#pragma unroll
          for (int r = 0; r < 4; ++r) o[r] = f2b(v[r]);
          *(bf4*)&reinterpret_cast<short*>(Out)[idx] = o;
        }
      }
    }
  }
}

// ---------------------------------------------------------------------------
// Softmax over rows of 1024: fp32 sim in, bf16 P out.
__global__ __launch_bounds__(256) void softmax1024(const float* __restrict__ sim,
                                                   short* __restrict__ P) {
  const float* row = sim + (size_t)blockIdx.x * 1024;
  int t = threadIdx.x;
  float4 v = ((const float4*)row)[t];
  float m = fmaxf(fmaxf(v.x, v.y), fmaxf(v.z, v.w));
  m = wave_max(m);
  __shared__ float red[4], red2[4];
  int wid = t >> 6, lane = t & 63;
  if (lane == 0) red[wid] = m;
  __syncthreads();
  m = fmaxf(fmaxf(red[0], red[1]), fmaxf(red[2], red[3]));
  v.x = __expf(v.x - m); v.y = __expf(v.y - m);
  v.z = __expf(v.z - m); v.w = __expf(v.w - m);
  float s = v.x + v.y + v.z + v.w;
  s = wave_sum(s);
  if (lane == 0) red2[wid] = s;
  __syncthreads();
  s = red2[0] + red2[1] + red2[2] + red2[3];
  float inv = 1.f / s;
  bf4 o;
  o[0] = f2b(v.x * inv); o[1] = f2b(v.y * inv);
  o[2] = f2b(v.z * inv); o[3] = f2b(v.w * inv);
  ((bf4*)(P + (size_t)blockIdx.x * 1024))[t] = o;
}

// ---------------------------------------------------------------------------
// Fused cross-attention via MFMA: per (b, h, 64 q-rows); 4 waves x 16 q-rows.
// QK^T frags loaded directly from global (A-layout m=lane&15, k=quad*8 matches
// row-major [n][512]); softmax in-register (16-lane shuffle); P->LDS round-trip
// into A-operand layout; V transposed into LDS once; 12 MFMAs for PV.
// Row stride 104 shorts (208 B) keeps ds_read_b128 conflicts <= 2-way.
__global__ __launch_bounds__(256) void cross_attn_mfma(const short* __restrict__ q2,
                                                       const short* __restrict__ k2,
                                                       const short* __restrict__ v2,
                                                       short* __restrict__ o2) {
  __shared__ short Pl[64 * 104];
  __shared__ short VTl[64 * 104];
  const int b = blockIdx.z, h = blockIdx.y, i0 = blockIdx.x * 64;
  const int tid = threadIdx.x;
  const int w = tid >> 6, l = tid & 63, lm = l & 15, quad = l >> 4;

  // zero VT (incl. padding cols), then scatter-transpose V into it
  for (int idx = tid; idx < 64 * 104 / 4; idx += 256)
    *(bf4*)&VTl[idx * 4] = (bf4){0, 0, 0, 0};
  __syncthreads();
  for (int idx = tid; idx < 77 * 64; idx += 256) {
    int j = idx >> 6, d = idx & 63;
    VTl[d * 104 + j] = v2[(size_t)b * 39424 + j * 512 + h * 64 + d];
  }

  // scores: S[q][j] = 0.125 * sum_d Q[q][d] K[j][d]
  const short* qb = q2 + ((size_t)b * 1024 + i0 + w * 16 + lm) * 512 + h * 64;
  bf8 aq0 = *(const bf8*)&qb[quad * 8];
  bf8 aq1 = *(const bf8*)&qb[32 + quad * 8];
  const short* kb = k2 + (size_t)b * 39424 + h * 64;
  f32x4 sacc[5];
#pragma unroll
  for (int jt = 0; jt < 5; ++jt) sacc[jt] = (f32x4){0.f, 0.f, 0.f, 0.f};
#pragma unroll
  for (int jt = 0; jt < 5; ++jt) {
    int j = jt * 16 + lm;
    bf8 b0 = {0, 0, 0, 0, 0, 0, 0, 0}, b1 = {0, 0, 0, 0, 0, 0, 0, 0};
    if (j < 77) {
      b0 = *(const bf8*)&kb[j * 512 + quad * 8];
      b1 = *(const bf8*)&kb[j * 512 + 32 + quad * 8];
    }
    sacc[jt] = __builtin_amdgcn_mfma_f32_16x16x32_bf16(aq0, b0, sacc[jt], 0, 0, 0);
    sacc[jt] = __builtin_amdgcn_mfma_f32_16x16x32_bf16(aq1, b1, sacc[jt], 0, 0, 0);
  }
  // mask + scale
#pragma unroll
  for (int jt = 0; jt < 5; ++jt) {
    bool valid = (jt * 16 + lm) < 77;
#pragma unroll
    for (int r = 0; r < 4; ++r)
      sacc[jt][r] = valid ? sacc[jt][r] * 0.125f : -1e30f;
  }
  // softmax per q-row (row = quad*4+r; j spread over 16 lanes x 5 tiles)
#pragma unroll
  for (int r = 0; r < 4; ++r) {
    float mx = sacc[0][r];
#pragma unroll
    for (int jt = 1; jt < 5; ++jt) mx = fmaxf(mx, sacc[jt][r]);
    mx = fmaxf(mx, __shfl_xor(mx, 1));
    mx = fmaxf(mx, __shfl_xor(mx, 2));
    mx = fmaxf(mx, __shfl_xor(mx, 4));
    mx = fmaxf(mx, __shfl_xor(mx, 8));
    float s = 0.f;
    float e[5];
#pragma unroll
    for (int jt = 0; jt < 5; ++jt) { e[jt] = __expf(sacc[jt][r] - mx); s += e[jt]; }
    s += __shfl_xor(s, 1);
    s += __shfl_xor(s, 2);
    s += __shfl_xor(s, 4);
    s += __shfl_xor(s, 8);
    float iv = 1.f / s;
    int row = w * 16 + quad * 4 + r;
#pragma unroll
    for (int jt = 0; jt < 5; ++jt) Pl[row * 104 + jt * 16 + lm] = f2b(e[jt] * iv);
  }
  // zero P cols 80..95 (read by the 3rd PV k-chunk)
#pragma unroll
  for (int r = 0; r < 4; ++r) Pl[(w * 16 + quad * 4 + r) * 104 + 80 + lm] = 0;
  __syncthreads();

  // PV: O[q][d] = sum_j P[q][j] VT[d][j], j padded to 96
  f32x4 oacc[4];
#pragma unroll
  for (int dt = 0; dt < 4; ++dt) oacc[dt] = (f32x4){0.f, 0.f, 0.f, 0.f};
#pragma unroll
  for (int kc = 0; kc < 3; ++kc) {
    bf8 ap = *(const bf8*)&Pl[(w * 16 + lm) * 104 + kc * 32 + quad * 8];
#pragma unroll
    for (int dt = 0; dt < 4; ++dt) {
      bf8 bv = *(const bf8*)&VTl[(dt * 16 + lm) * 104 + kc * 32 + quad * 8];
      oacc[dt] = __builtin_amdgcn_mfma_f32_16x16x32_bf16(ap, bv, oacc[dt], 0, 0, 0);
    }
  }
  short* ob = o2 + ((size_t)b * 1024 + i0 + w * 16 + quad * 4) * 512 + h * 64;
#pragma unroll
  for (int dt = 0; dt < 4; ++dt)
#pragma unroll
    for (int r = 0; r < 4; ++r)
      ob[(size_t)r * 512 + dt * 16 + lm] = f2b(oacc[dt][r]);
}

// ---------------------------------------------------------------------------
extern "C" void kernel_launch(void* const* d_in, const int* in_sizes, int n_in,
                              void* d_out, int out_size, void* d_ws, size_t ws_size,
                              hipStream_t stream) {
  const void* x       = d_in[0];
  const void* ctx     = d_in[1];
  const void* gn1_g   = d_in[2];
  const void* gn1_b   = d_in[3];
  const void* w_in    = d_in[4];
  const void* b_in    = d_in[5];
  const void* sa_wk   = d_in[6];
  const void* sa_wq   = d_in[7];
  const void* sa_wv   = d_in[8];
  const void* sa_wp   = d_in[9];
  const void* sa_gn_g = d_in[10];
  const void* sa_gn_b = d_in[11];
  const void* ca_wq   = d_in[12];
  const void* ca_wk   = d_in[13];
  const void* ca_wv   = d_in[14];
  const void* ca_wo   = d_in[15];
  const void* ca_bo   = d_in[16];
  const void* w_out   = d_in[17];
  const void* b_out   = d_in[18];

  const int B = 16;
  // footprint = 128KB + NB * 11 MB
  int NB = 16;
  while (NB > 1 && 131072ull + (size_t)NB * 11534336ull > ws_size) NB >>= 1;

  char* base = reinterpret_cast<char*>(d_ws);
  int* flagp = reinterpret_cast<int*>(base);
  float* smf = reinterpret_cast<float*>(base + 1024);
  float* stats1 = smf;
  float* stats2 = smf + 1024;
  float* s1 = smf + 2048;
  float* t1 = smf + 6144;
  float* s2 = smf + 10240;
  float* t2 = smf + 18432;
  char* big = base + 131072;
  const size_t MB = 1048576;
  short* U0 = (short*)(big + 0 * (size_t)NB * MB);  // h1 -> h3
  short* U1 = (short*)(big + 1 * (size_t)NB * MB);  // h1g -> o_attn
  short* U2 = (short*)(big + 2 * (size_t)NB * MB);  // q -> q2
  short* U3 = (short*)(big + 3 * (size_t)NB * MB);  // k -> h2
  short* U4 = (short*)(big + 4 * (size_t)NB * MB);  // vT -> o2
  char* Sreg = big + 5 * (size_t)NB * MB;           // 6 MB/b region
  float* simb = (float*)Sreg;                          // [NB,1024,1024] fp32
  short* Pbuf = (short*)(Sreg + (size_t)NB * 4 * MB);  // [NB,1024,1024] bf16
  short* xT = (short*)Sreg;                            // [NB,1024,256] bf16 (pre-sim)
  short* k2 = (short*)Sreg;                            // [NB,77,512] bf16 (post-sim)
  short* v2 = (short*)(Sreg + (size_t)NB * 78848);

  probe_dtype<<<1, 256, 0, stream>>>((const unsigned short*)x, flagp);

  const float qk_scale = 0.044194173824159216f;  // 512^-0.5

  for (int b0 = 0; b0 < B; b0 += NB) {
    size_t xoff = (size_t)b0 * 262144;  // CIN*N
    size_t coff = (size_t)b0 * 59136;   // 77*768

    // GN1 + conv_in
    gn_stats_ext<<<NB * 32, 256, 0, stream>>>(x, xoff, flagp, stats1, 8, 256, 1024, 32);
    make_affine<<<(NB * 256 + 255) / 256, 256, 0, stream>>>(stats1, gn1_g, gn1_b, flagp, s1, t1, 256, 8, NB * 256);
    transpose_affine<<<dim3(16, NB), 256, 0, stream>>>(x, xoff, flagp, s1, t1, xT);
    mm<1, 0, 0, 0, 1, 0><<<dim3(4, 8, NB), 256, 0, stream>>>(
        w_in, 0, 256, 0, xT, 0, 256, 262144, U0, 0, 512, 524288,
        nullptr, 0, 0, 0.f, nullptr, b_in, flagp, 1.f, 1024, 256);

    // GN2 -> h1g
    gn_stats2<<<NB * 32, 256, 0, stream>>>(U0, stats2);
    make_affine<<<(NB * 512 + 255) / 256, 256, 0, stream>>>(stats2, sa_gn_g, sa_gn_b, flagp, s2, t2, 512, 16, NB * 512);
    affine_apply<<<NB * 512, 256, 0, stream>>>(U0, s2, t2, U1);

    // q, k, vT
    mm<1, 0, 0, 0, 0, 0><<<dim3(4, 8, NB), 256, 0, stream>>>(
        sa_wq, 0, 512, 0, U1, 0, 512, 524288, U2, 0, 512, 524288,
        nullptr, 0, 0, 0.f, nullptr, nullptr, flagp, 1.f, 1024, 512);
    mm<1, 0, 0, 0, 0, 0><<<dim3(4, 8, NB), 256, 0, stream>>>(
        sa_wk, 0, 512, 0, U1, 0, 512, 524288, U3, 0, 512, 524288,
        nullptr, 0, 0, 0.f, nullptr, nullptr, flagp, 1.f, 1024, 512);
    mm<0, 1, 0, 0, 0, 0><<<dim3(8, 4, NB), 256, 0, stream>>>(
        U1, 0, 512, 524288, sa_wv, 0, 512, 0, U4, 0, 1024, 524288,
        nullptr, 0, 0, 0.f, nullptr, nullptr, flagp, 1.f, 512, 512);

    // sim = scale*q@k^T ; softmax -> P ; o = P@v
    mm<0, 0, 1, 0, 0, 0><<<dim3(8, 8, NB), 256, 0, stream>>>(
        U3, 0, 512, 524288, U2, 0, 512, 524288, simb, 0, 1024, 1048576,
        nullptr, 0, 0, 0.f, nullptr, nullptr, flagp, qk_scale, 1024, 512);
    softmax1024<<<NB * 1024, 256, 0, stream>>>(simb, Pbuf);
    mm<0, 0, 0, 0, 0, 0><<<dim3(4, 8, NB), 256, 0, stream>>>(
        U4, 0, 1024, 524288, Pbuf, 0, 1024, 1048576, U1, 0, 512, 524288,
        nullptr, 0, 0, 0.f, nullptr, nullptr, flagp, 1.f, 1024, 1024);

    // h2 = wp@o + 2*h1
    mm<1, 0, 0, 0, 0, 1><<<dim3(4, 8, NB), 256, 0, stream>>>(
        sa_wp, 0, 512, 0, U1, 0, 512, 524288, U3, 0, 512, 524288,
        U0, 0, 524288, 2.f, nullptr, nullptr, flagp, 1.f, 1024, 512);

    // cross-attn
    mm<1, 0, 0, 0, 0, 0><<<dim3(4, 8, NB), 256, 0, stream>>>(
        ca_wq, 0, 512, 0, U3, 0, 512, 524288, U2, 0, 512, 524288,
        nullptr, 0, 0, 0.f, nullptr, nullptr, flagp, 1.f, 1024, 512);
    mm<1, 1, 0, 0, 0, 0><<<dim3(4, 1, NB), 256, 0, stream>>>(
        ca_wk, 0, 768, 0, ctx, coff, 768, 59136, k2, 0, 512, 39424,
        nullptr, 0, 0, 0.f, nullptr, nullptr, flagp, 1.f, 77, 768);
    mm<1, 1, 0, 0, 0, 0><<<dim3(4, 1, NB), 256, 0, stream>>>(
        ca_wv, 0, 768, 0, ctx, coff, 768, 59136, v2, 0, 512, 39424,
        nullptr, 0, 0, 0.f, nullptr, nullptr, flagp, 1.f, 77, 768);
    cross_attn_mfma<<<dim3(16, 8, NB), 256, 0, stream>>>(U2, k2, v2, U4);

    // h3 = wo@o2 + bo + h2
    mm<1, 0, 0, 0, 1, 1><<<dim3(4, 8, NB), 256, 0, stream>>>(
        ca_wo, 0, 512, 0, U4, 0, 512, 524288, U0, 0, 512, 524288,
        U3, 0, 524288, 1.f, nullptr, ca_bo, flagp, 1.f, 1024, 512);

    // y = w_out@h3 + b_out + x
    mm<0, 1, 2, 1, 0, 2><<<dim3(8, 2, NB), 256, 0, stream>>>(
        U0, 0, 512, 524288, w_out, 0, 512, 0, d_out, xoff, 1024, 262144,
        x, xoff, 262144, 1.f, b_out, nullptr, flagp, 1.f, 256, 512);
  }

  (void)in_sizes; (void)n_in; (void)out_size;
}